// Round 2
// baseline (433.611 us; speedup 1.0000x reference)
//
#include <hip/hip_runtime.h>
#include <hip/hip_cooperative_groups.h>

namespace cg = cooperative_groups;

#define HH 2048
#define WW 2048
#define WPR 32  // 64-bit words per image row (2048/64)

typedef unsigned long long u64;

// ---------------- Kernel 1: quantize + Sobel + NMS + double threshold ----------------
// Produces bitmaps: weakG (mag>100 & keep & interior), edgeG (initialized to strong).
__global__ __launch_bounds__(256) void canny_prep(
    const float* __restrict__ x, u64* __restrict__ weakG,
    u64* __restrict__ edgeG, unsigned int* __restrict__ flags)
{
    __shared__ int imgS[20][68];  // img tile + halo 2 (replicate-clamped)
    __shared__ int magS[18][68];  // |gx|+|gy| tile + halo 1 (cols 0..65 used)
    const int tid = threadIdx.x;
    const int tx0 = blockIdx.x * 64;
    const int ty0 = blockIdx.y * 16;

    if (blockIdx.x == 0 && blockIdx.y == 0 && tid < 2) flags[tid] = 0u;

    // stage quantized image (exact fp32 replication of floor(x*255) clip)
    for (int idx = tid; idx < 20 * 68; idx += 256) {
        int r = idx / 68, c = idx - r * 68;
        int gy = ty0 - 2 + r; gy = gy < 0 ? 0 : (gy > HH - 1 ? HH - 1 : gy);
        int gx = tx0 - 2 + c; gx = gx < 0 ? 0 : (gx > WW - 1 ? WW - 1 : gx);
        float v = floorf(x[gy * WW + gx] * 255.0f);
        v = fminf(fmaxf(v, 0.0f), 255.0f);
        imgS[r][c] = (int)v;
    }
    __syncthreads();

    // L1 gradient magnitude for tile + halo 1 (integer exact)
    for (int idx = tid; idx < 18 * 66; idx += 256) {
        int r = idx / 66, c = idx - r * 66;
        int a00 = imgS[r][c],     a01 = imgS[r][c + 1],     a02 = imgS[r][c + 2];
        int a10 = imgS[r + 1][c],                           a12 = imgS[r + 1][c + 2];
        int a20 = imgS[r + 2][c], a21 = imgS[r + 2][c + 1], a22 = imgS[r + 2][c + 2];
        int gxv = (a02 + 2 * a12 + a22) - (a00 + 2 * a10 + a20);
        int gyv = (a20 + 2 * a21 + a22) - (a00 + 2 * a01 + a02);
        magS[r][c] = abs(gxv) + abs(gyv);
    }
    __syncthreads();

    const int lane = tid & 63;
    const int wv = tid >> 6;
    for (int i = 0; i < 4; ++i) {
        int rr = wv * 4 + i;        // tile row 0..15
        int gyp = ty0 + rr;         // global row
        int r = rr + 1, c = lane + 1;  // mag coords of center
        // gradient at center pixel
        int a00 = imgS[rr + 1][lane + 1], a01 = imgS[rr + 1][lane + 2], a02 = imgS[rr + 1][lane + 3];
        int a10 = imgS[rr + 2][lane + 1],                               a12 = imgS[rr + 2][lane + 3];
        int a20 = imgS[rr + 3][lane + 1], a21 = imgS[rr + 3][lane + 2], a22 = imgS[rr + 3][lane + 3];
        int gxv = (a02 + 2 * a12 + a22) - (a00 + 2 * a10 + a20);
        int gyv = (a20 + 2 * a21 + a22) - (a00 + 2 * a01 + a02);
        int mag = magS[r][c];

        // exact direction class: ang = atan2(gy,gx) deg mod 180
        // 0: [0,22.5)|[157.5,180)  1: [22.5,67.5)  2: [67.5,112.5)  3: [112.5,157.5)
        // tan(22.5)=sqrt2-1, tan(67.5)=sqrt2+1 -> integer-exact square comparisons
        int ay = gyv, ax = gxv;
        if (ay < 0) { ay = -ay; ax = -ax; }
        int cls;
        if (ay == 0) cls = 0;
        else if (ax > 0) {
            long long s = ay + ax, q = 2LL * ax * ax;
            if (s * s < q) cls = 0;                      // ay < ax*(sqrt2-1)
            else { long long t = ay - ax; cls = (t < 0 || t * t < q) ? 1 : 2; }
        } else if (ax == 0) cls = 2;
        else {
            long long h = -(long long)ax, s = ay + h, q = 2LL * h * h;
            if (s * s < q) cls = 0;                      // ang >= 157.5
            else { long long t = ay - h; cls = (t > 0 && t * t > q) ? 2 : 3; }
        }
        int n1, n2;
        if (cls == 0)      { n1 = magS[r][c + 1];     n2 = magS[r][c - 1]; }
        else if (cls == 1) { n1 = magS[r - 1][c + 1]; n2 = magS[r + 1][c - 1]; }
        else if (cls == 2) { n1 = magS[r - 1][c];     n2 = magS[r + 1][c]; }
        else               { n1 = magS[r - 1][c - 1]; n2 = magS[r + 1][c + 1]; }

        bool keep = (mag >= n1) && (mag > n2) && (gyp > 0) && (gyp < HH - 1);
        bool weak = keep && (mag > 100);
        bool strong = keep && (mag > 200);
        u64 ww = __ballot(weak);
        u64 sw = __ballot(strong);
        if (lane == 0) {
            u64 m = ~0ull;
            if (tx0 == 0) m &= ~1ull;              // col 0 never edge
            if (tx0 + 64 == WW) m &= ~(1ull << 63); // col 2047 never edge
            int widx = gyp * WPR + (tx0 >> 6);
            weakG[widx] = ww & m;
            edgeG[widx] = sw & m;
        }
    }
}

// ---------------- Kernel 2 (cooperative): hysteresis fixpoint + output write ----------------
__global__ __launch_bounds__(256) void canny_hyst(
    const u64* __restrict__ weakG, u64* __restrict__ edgeG,
    unsigned int* __restrict__ flags, float* __restrict__ out)
{
    cg::grid_group grid = cg::this_grid();
    const int tid = threadIdx.x;
    const int b = blockIdx.x;     // 256 blocks, 8 rows each
    const int r = tid >> 5;       // 0..7
    const int c = tid & 31;       // 0..31
    const int row0 = b * 8;
    __shared__ u64 weakL[8][32];
    __shared__ u64 edgeL[10][32]; // rows 0 and 9 are neighbor-slab boundary rows
    __shared__ int sChg[2];       // parity double-buffered block-change flag
    __shared__ int sAny;

    weakL[r][c] = weakG[(row0 + r) * WPR + c];
    edgeL[r + 1][c] = edgeG[(row0 + r) * WPR + c];

    int iter = 0;
    for (;;) {
        // fresh boundary rows from neighboring slabs
        if (tid < 32) {
            u64 v = 0;
            if (b > 0) v = __hip_atomic_load(&edgeG[(row0 - 1) * WPR + tid],
                                             __ATOMIC_RELAXED, __HIP_MEMORY_SCOPE_AGENT);
            edgeL[0][tid] = v;
        } else if (tid < 64) {
            int cc = tid - 32;
            u64 v = 0;
            if (b < (int)gridDim.x - 1)
                v = __hip_atomic_load(&edgeG[(row0 + 8) * WPR + cc],
                                      __ATOMIC_RELAXED, __HIP_MEMORY_SCOPE_AGENT);
            edgeL[9][cc] = v;
        }
        if (tid == 0) sAny = 0;
        if (tid < 2) sChg[tid] = 0;
        __syncthreads();

        // block-local fixpoint (word-parallel 3x3 dilation, monotone).
        // Parity-double-buffered change flag: writers set sChg[p]; tid0 clears
        // sChg[p^1] BEFORE the barrier; readers read sChg[p] AFTER it. The
        // slot a thread reads is never written again until one full iteration
        // (two barriers) later -> no read/reset race, no barrier divergence.
        int p = 0;
        for (;;) {
            u64 up = edgeL[r][c],     upl = c ? edgeL[r][c - 1] : 0,     upr = (c < 31) ? edgeL[r][c + 1] : 0;
            u64 mi = edgeL[r + 1][c], mil = c ? edgeL[r + 1][c - 1] : 0, mir = (c < 31) ? edgeL[r + 1][c + 1] : 0;
            u64 dn = edgeL[r + 2][c], dnl = c ? edgeL[r + 2][c - 1] : 0, dnr = (c < 31) ? edgeL[r + 2][c + 1] : 0;
            u64 A = up | (up << 1) | (up >> 1) | (upl >> 63) | (upr << 63);
            u64 B = mi | (mi << 1) | (mi >> 1) | (mil >> 63) | (mir << 63);
            u64 C = dn | (dn << 1) | (dn >> 1) | (dnl >> 63) | (dnr << 63);
            u64 ne = mi | (weakL[r][c] & (A | B | C));
            bool chg = (ne != mi);
            __syncthreads();               // reads above complete before writes below
            edgeL[r + 1][c] = ne;
            if (chg) { sChg[p] = 1; sAny = 1; }
            if (tid == 0) sChg[p ^ 1] = 0; // clear NEXT slot (not the one being read)
            __syncthreads();
            if (!sChg[p]) break;           // uniform: slot stable until 2 barriers later
            p ^= 1;
        }

        if (sAny) edgeG[(row0 + r) * WPR + c] = edgeL[r + 1][c];
        if (sAny && tid == 0) atomicOr(&flags[iter & 1], 1u);
        __threadfence();
        grid.sync();
        unsigned f = __hip_atomic_load(&flags[iter & 1], __ATOMIC_ACQUIRE, __HIP_MEMORY_SCOPE_AGENT);
        if (tid == 0) flags[(iter + 1) & 1] = 0u;  // prep next-parity flag
        __threadfence();
        grid.sync();
        if (f == 0) break;
        ++iter;
    }

    // fused output write: 0/1 floats broadcast to 3 channels, coalesced float4
    for (int chn = 0; chn < 3; ++chn) {
        for (int rr = 0; rr < 8; ++rr) {
            size_t base = ((size_t)chn * HH + (size_t)(row0 + rr)) * WW;
            for (int k = tid; k < 512; k += 256) {
                u64 w = edgeL[rr + 1][k >> 4];
                int sh = (k & 15) * 4;
                float4 v;
                v.x = (float)((w >> sh) & 1ull);
                v.y = (float)((w >> (sh + 1)) & 1ull);
                v.z = (float)((w >> (sh + 2)) & 1ull);
                v.w = (float)((w >> (sh + 3)) & 1ull);
                *reinterpret_cast<float4*>(out + base + (size_t)k * 4) = v;
            }
        }
    }
}

extern "C" void kernel_launch(void* const* d_in, const int* in_sizes, int n_in,
                              void* d_out, int out_size, void* d_ws, size_t ws_size,
                              hipStream_t stream) {
    const float* x = (const float*)d_in[0];
    float* out = (float*)d_out;
    u64* edgeG = (u64*)d_ws;                       // 512 KB
    u64* weakG = edgeG + (size_t)HH * WPR;         // 512 KB
    unsigned int* flags = (unsigned int*)(weakG + (size_t)HH * WPR);

    hipLaunchKernelGGL(canny_prep, dim3(WW / 64, HH / 16), dim3(256), 0, stream,
                       x, weakG, edgeG, flags);

    void* args[] = { (void*)&weakG, (void*)&edgeG, (void*)&flags, (void*)&out };
    hipLaunchCooperativeKernel((void*)canny_hyst, dim3(256), dim3(256), args, 0, stream);
}

// Round 3
// 426.174 us; speedup vs baseline: 1.0174x; 1.0174x over previous
//
#include <hip/hip_runtime.h>
#include <hip/hip_cooperative_groups.h>

namespace cg = cooperative_groups;

#define HH 2048
#define WW 2048
#define WPR 32            // 64-bit words per image row
#define NPIX (HH * WW)    // 4194304
#define NWORDS (HH * WPR) // 65536

typedef unsigned long long u64;
typedef unsigned int u32;

// ---------------- union-find primitives (ECL-CC style, lock-free) ----------------
// Invariant: f[i] <= i always (links only point to smaller indices) -> acyclic,
// guaranteed termination. CAS only targets roots; failed CAS returns the fresh
// parent so progress never depends on possibly-stale cached plain loads.
__device__ inline int findRoot(int* __restrict__ f, int i) {
    int p = __hip_atomic_load(&f[i], __ATOMIC_RELAXED, __HIP_MEMORY_SCOPE_AGENT);
    while (p != i) {
        int gp = __hip_atomic_load(&f[p], __ATOMIC_RELAXED, __HIP_MEMORY_SCOPE_AGENT);
        if (gp != p)
            __hip_atomic_store(&f[i], gp, __ATOMIC_RELAXED, __HIP_MEMORY_SCOPE_AGENT); // path halving
        i = p; p = gp;
    }
    return i;
}

__device__ inline void unite(int* __restrict__ f, int a, int b) {
    int ra = findRoot(f, a), rb = findRoot(f, b);
    while (ra != rb) {
        if (ra > rb) { int t = ra; ra = rb; rb = t; }
        int old = atomicCAS(&f[rb], rb, ra);
        if (old == rb || old == ra) return;
        rb = findRoot(f, old);   // old is FRESH (atomic) -> guaranteed progress
    }
}

// ---------------- Kernel 1: quantize + Sobel + NMS + double threshold ----------------
// weakG: keep & mag>100 ; strongG: keep & mag>200 (strong subset of weak).
// Also inits union-find labels f[i]=i and zeroes markBits (when provided).
__global__ __launch_bounds__(256) void canny_prep(
    const float* __restrict__ x, u64* __restrict__ weakG,
    u64* __restrict__ strongG, unsigned int* __restrict__ flags,
    int* __restrict__ f, u32* __restrict__ markBits)
{
    __shared__ int imgS[20][68];  // img tile + halo 2 (replicate-clamped)
    __shared__ int magS[18][68];  // |gx|+|gy| tile + halo 1
    const int tid = threadIdx.x;
    const int tx0 = blockIdx.x * 64;
    const int ty0 = blockIdx.y * 16;

    if (flags && blockIdx.x == 0 && blockIdx.y == 0 && tid < 2) flags[tid] = 0u;
    if (markBits) {  // zero 512KB across the 4096 blocks: 32 words each
        int bid = blockIdx.y * gridDim.x + blockIdx.x;
        if (tid < 32) markBits[bid * 32 + tid] = 0u;
    }

    // stage quantized image (exact fp32 replication of floor(x*255) clip)
    for (int idx = tid; idx < 20 * 68; idx += 256) {
        int r = idx / 68, c = idx - r * 68;
        int gy = ty0 - 2 + r; gy = gy < 0 ? 0 : (gy > HH - 1 ? HH - 1 : gy);
        int gx = tx0 - 2 + c; gx = gx < 0 ? 0 : (gx > WW - 1 ? WW - 1 : gx);
        float v = floorf(x[gy * WW + gx] * 255.0f);
        v = fminf(fmaxf(v, 0.0f), 255.0f);
        imgS[r][c] = (int)v;
    }
    __syncthreads();

    // L1 gradient magnitude for tile + halo 1 (integer exact)
    for (int idx = tid; idx < 18 * 66; idx += 256) {
        int r = idx / 66, c = idx - r * 66;
        int a00 = imgS[r][c],     a01 = imgS[r][c + 1],     a02 = imgS[r][c + 2];
        int a10 = imgS[r + 1][c],                           a12 = imgS[r + 1][c + 2];
        int a20 = imgS[r + 2][c], a21 = imgS[r + 2][c + 1], a22 = imgS[r + 2][c + 2];
        int gxv = (a02 + 2 * a12 + a22) - (a00 + 2 * a10 + a20);
        int gyv = (a20 + 2 * a21 + a22) - (a00 + 2 * a01 + a02);
        magS[r][c] = abs(gxv) + abs(gyv);
    }
    __syncthreads();

    const int lane = tid & 63;
    const int wv = tid >> 6;
    for (int i = 0; i < 4; ++i) {
        int rr = wv * 4 + i;        // tile row 0..15
        int gyp = ty0 + rr;         // global row
        int r = rr + 1, c = lane + 1;
        int a00 = imgS[rr + 1][lane + 1], a01 = imgS[rr + 1][lane + 2], a02 = imgS[rr + 1][lane + 3];
        int a10 = imgS[rr + 2][lane + 1],                               a12 = imgS[rr + 2][lane + 3];
        int a20 = imgS[rr + 3][lane + 1], a21 = imgS[rr + 3][lane + 2], a22 = imgS[rr + 3][lane + 3];
        int gxv = (a02 + 2 * a12 + a22) - (a00 + 2 * a10 + a20);
        int gyv = (a20 + 2 * a21 + a22) - (a00 + 2 * a01 + a02);
        int mag = magS[r][c];

        // exact direction class via tan(22.5)=sqrt2-1, tan(67.5)=sqrt2+1 (integer squares)
        int ay = gyv, ax = gxv;
        if (ay < 0) { ay = -ay; ax = -ax; }
        int cls;
        if (ay == 0) cls = 0;
        else if (ax > 0) {
            long long s = ay + ax, q = 2LL * ax * ax;
            if (s * s < q) cls = 0;
            else { long long t = ay - ax; cls = (t < 0 || t * t < q) ? 1 : 2; }
        } else if (ax == 0) cls = 2;
        else {
            long long h = -(long long)ax, s = ay + h, q = 2LL * h * h;
            if (s * s < q) cls = 0;
            else { long long t = ay - h; cls = (t > 0 && t * t > q) ? 2 : 3; }
        }
        int n1, n2;
        if (cls == 0)      { n1 = magS[r][c + 1];     n2 = magS[r][c - 1]; }
        else if (cls == 1) { n1 = magS[r - 1][c + 1]; n2 = magS[r + 1][c - 1]; }
        else if (cls == 2) { n1 = magS[r - 1][c];     n2 = magS[r + 1][c]; }
        else               { n1 = magS[r - 1][c - 1]; n2 = magS[r + 1][c + 1]; }

        bool keep = (mag >= n1) && (mag > n2) && (gyp > 0) && (gyp < HH - 1);
        bool weak = keep && (mag > 100);
        bool strong = keep && (mag > 200);
        u64 ww = __ballot(weak);
        u64 sw = __ballot(strong);
        if (f) f[gyp * WW + tx0 + lane] = gyp * WW + tx0 + lane;  // label init
        if (lane == 0) {
            u64 m = ~0ull;
            if (tx0 == 0) m &= ~1ull;
            if (tx0 + 64 == WW) m &= ~(1ull << 63);
            int widx = gyp * WPR + (tx0 >> 6);
            weakG[widx] = ww & m;
            strongG[widx] = sw & m;
        }
    }
}

// ---------------- Kernel 2: word-parallel neighbor unions ----------------
__global__ __launch_bounds__(256) void canny_merge(
    const u64* __restrict__ weakG, int* __restrict__ f)
{
    int t = blockIdx.x * 256 + threadIdx.x;   // 0..65535 (one 64px word)
    u64 w = weakG[t];
    if (!w) return;
    int y = t >> 5, c = t & 31;
    u64 wr = (c < 31) ? weakG[t + 1] : 0;
    u64 below = 0, belowl = 0, belowr = 0;
    if (y < HH - 1) {
        below  = weakG[t + WPR];
        belowl = c ? weakG[t + WPR - 1] : 0;
        belowr = (c < 31) ? weakG[t + WPR + 1] : 0;
    }
    int base = y * WW + c * 64;

    u64 mh = w & (w >> 1);                                   // horizontal pairs
    while (mh) { int b = __builtin_ctzll(mh); mh &= mh - 1; unite(f, base + b, base + b + 1); }
    if (((w >> 63) & wr & 1ull)) unite(f, base + 63, base + 64);
    u64 mv = w & below;                                      // down
    while (mv) { int b = __builtin_ctzll(mv); mv &= mv - 1; unite(f, base + b, base + b + WW); }
    u64 mdl = w & ((below << 1) | (belowl >> 63));           // down-left
    while (mdl) { int b = __builtin_ctzll(mdl); mdl &= mdl - 1; unite(f, base + b, base + b + WW - 1); }
    u64 mdr = w & ((below >> 1) | (belowr << 63));           // down-right
    while (mdr) { int b = __builtin_ctzll(mdr); mdr &= mdr - 1; unite(f, base + b, base + b + WW + 1); }
}

// ---------------- Kernel 3: flag roots of components containing a strong pixel ----
__global__ __launch_bounds__(256) void canny_flag(
    const u64* __restrict__ strongG, int* __restrict__ f, u32* __restrict__ markBits)
{
    int t = blockIdx.x * 256 + threadIdx.x;
    u64 s = strongG[t];
    if (!s) return;
    int y = t >> 5, c = t & 31;
    int base = y * WW + c * 64;
    int lastr = -1;
    while (s) {
        int b = __builtin_ctzll(s); s &= s - 1;
        int r = findRoot(f, base + b);
        if (r != lastr) { atomicOr(&markBits[r >> 5], 1u << (r & 31)); lastr = r; }
    }
}

// ---------------- Kernel 4: weak pixels -> edge bitmap via root flag ----------------
__global__ __launch_bounds__(256) void canny_edgebits(
    const u64* __restrict__ weakG, int* __restrict__ f,
    const u32* __restrict__ markBits, u64* __restrict__ edgeBits)
{
    int t = blockIdx.x * 256 + threadIdx.x;
    u64 w = weakG[t];
    u64 e = 0;
    int y = t >> 5, c = t & 31;
    int base = y * WW + c * 64;
    int lastr = -1; u64 lastfl = 0;
    while (w) {
        int b = __builtin_ctzll(w); w &= w - 1;
        int r = findRoot(f, base + b);
        if (r != lastr) { lastr = r; lastfl = (markBits[r >> 5] >> (r & 31)) & 1u; }
        e |= lastfl << b;
    }
    edgeBits[t] = e;
}

// ---------------- Kernel 5: expand bitmap -> 3x fp32 channels (pure BW) -------------
__global__ __launch_bounds__(256) void canny_expand(
    const u64* __restrict__ edgeBits, float* __restrict__ out)
{
    int t = blockIdx.x * 256 + threadIdx.x;   // 0..262143, 16 px each
    int px = t << 4;
    u64 w = edgeBits[px >> 6];
    u32 bits = (u32)(w >> (px & 63)) & 0xFFFFu;
    float4 v[4];
    #pragma unroll
    for (int q = 0; q < 4; ++q) {
        v[q].x = (float)((bits >> (q * 4 + 0)) & 1u);
        v[q].y = (float)((bits >> (q * 4 + 1)) & 1u);
        v[q].z = (float)((bits >> (q * 4 + 2)) & 1u);
        v[q].w = (float)((bits >> (q * 4 + 3)) & 1u);
    }
    #pragma unroll
    for (int ch = 0; ch < 3; ++ch) {
        float4* p = reinterpret_cast<float4*>(out + (size_t)ch * NPIX + px);
        p[0] = v[0]; p[1] = v[1]; p[2] = v[2]; p[3] = v[3];
    }
}

// ---------------- Fallback (small ws): proven cooperative hysteresis ----------------
__global__ __launch_bounds__(256) void canny_hyst(
    const u64* __restrict__ weakG, u64* __restrict__ edgeG,
    unsigned int* __restrict__ flags, float* __restrict__ out)
{
    cg::grid_group grid = cg::this_grid();
    const int tid = threadIdx.x;
    const int b = blockIdx.x;
    const int r = tid >> 5;
    const int c = tid & 31;
    const int row0 = b * 8;
    __shared__ u64 weakL[8][32];
    __shared__ u64 edgeL[10][32];
    __shared__ int sChg[2];
    __shared__ int sAny;

    weakL[r][c] = weakG[(row0 + r) * WPR + c];
    edgeL[r + 1][c] = edgeG[(row0 + r) * WPR + c];

    int iter = 0;
    for (;;) {
        if (tid < 32) {
            u64 v = 0;
            if (b > 0) v = __hip_atomic_load(&edgeG[(row0 - 1) * WPR + tid],
                                             __ATOMIC_RELAXED, __HIP_MEMORY_SCOPE_AGENT);
            edgeL[0][tid] = v;
        } else if (tid < 64) {
            int cc = tid - 32;
            u64 v = 0;
            if (b < (int)gridDim.x - 1)
                v = __hip_atomic_load(&edgeG[(row0 + 8) * WPR + cc],
                                      __ATOMIC_RELAXED, __HIP_MEMORY_SCOPE_AGENT);
            edgeL[9][cc] = v;
        }
        if (tid == 0) sAny = 0;
        if (tid < 2) sChg[tid] = 0;
        __syncthreads();

        int p = 0;
        for (;;) {
            u64 up = edgeL[r][c],     upl = c ? edgeL[r][c - 1] : 0,     upr = (c < 31) ? edgeL[r][c + 1] : 0;
            u64 mi = edgeL[r + 1][c], mil = c ? edgeL[r + 1][c - 1] : 0, mir = (c < 31) ? edgeL[r + 1][c + 1] : 0;
            u64 dn = edgeL[r + 2][c], dnl = c ? edgeL[r + 2][c - 1] : 0, dnr = (c < 31) ? edgeL[r + 2][c + 1] : 0;
            u64 A = up | (up << 1) | (up >> 1) | (upl >> 63) | (upr << 63);
            u64 B = mi | (mi << 1) | (mi >> 1) | (mil >> 63) | (mir << 63);
            u64 C = dn | (dn << 1) | (dn >> 1) | (dnl >> 63) | (dnr << 63);
            u64 ne = mi | (weakL[r][c] & (A | B | C));
            bool chg = (ne != mi);
            __syncthreads();
            edgeL[r + 1][c] = ne;
            if (chg) { sChg[p] = 1; sAny = 1; }
            if (tid == 0) sChg[p ^ 1] = 0;
            __syncthreads();
            if (!sChg[p]) break;
            p ^= 1;
        }

        if (sAny) edgeG[(row0 + r) * WPR + c] = edgeL[r + 1][c];
        if (sAny && tid == 0) atomicOr(&flags[iter & 1], 1u);
        __threadfence();
        grid.sync();
        unsigned fl = __hip_atomic_load(&flags[iter & 1], __ATOMIC_ACQUIRE, __HIP_MEMORY_SCOPE_AGENT);
        if (tid == 0) flags[(iter + 1) & 1] = 0u;
        __threadfence();
        grid.sync();
        if (fl == 0) break;
        ++iter;
    }

    for (int chn = 0; chn < 3; ++chn) {
        for (int rr = 0; rr < 8; ++rr) {
            size_t base2 = ((size_t)chn * HH + (size_t)(row0 + rr)) * WW;
            for (int k = tid; k < 512; k += 256) {
                u64 w = edgeL[rr + 1][k >> 4];
                int sh = (k & 15) * 4;
                float4 v;
                v.x = (float)((w >> sh) & 1ull);
                v.y = (float)((w >> (sh + 1)) & 1ull);
                v.z = (float)((w >> (sh + 2)) & 1ull);
                v.w = (float)((w >> (sh + 3)) & 1ull);
                *reinterpret_cast<float4*>(out + base2 + (size_t)k * 4) = v;
            }
        }
    }
}

extern "C" void kernel_launch(void* const* d_in, const int* in_sizes, int n_in,
                              void* d_out, int out_size, void* d_ws, size_t ws_size,
                              hipStream_t stream) {
    const float* x = (const float*)d_in[0];
    float* out = (float*)d_out;

    const size_t BM = (size_t)NWORDS * 8;          // 512 KB per bitmap
    const size_t need = 4 * BM + (size_t)NPIX * 4; // weak+strong+edge+mark + labels = 18 MB

    if (ws_size >= need) {
        u64* weakG   = (u64*)d_ws;
        u64* strongG = weakG + NWORDS;
        u64* edgeBits = strongG + NWORDS;
        u32* markBits = (u32*)(edgeBits + NWORDS);
        int* f = (int*)(markBits + NWORDS * 2);    // 512KB worth of u32 = NWORDS*2

        hipLaunchKernelGGL(canny_prep, dim3(WW / 64, HH / 16), dim3(256), 0, stream,
                           x, weakG, strongG, (unsigned int*)nullptr, f, markBits);
        hipLaunchKernelGGL(canny_merge, dim3(NWORDS / 256), dim3(256), 0, stream, weakG, f);
        hipLaunchKernelGGL(canny_flag, dim3(NWORDS / 256), dim3(256), 0, stream, strongG, f, markBits);
        hipLaunchKernelGGL(canny_edgebits, dim3(NWORDS / 256), dim3(256), 0, stream,
                           weakG, f, markBits, edgeBits);
        hipLaunchKernelGGL(canny_expand, dim3(NPIX / 16 / 256), dim3(256), 0, stream, edgeBits, out);
    } else {
        u64* edgeG = (u64*)d_ws;
        u64* weakG = edgeG + NWORDS;
        unsigned int* flags = (unsigned int*)(weakG + NWORDS);
        hipLaunchKernelGGL(canny_prep, dim3(WW / 64, HH / 16), dim3(256), 0, stream,
                           x, weakG, edgeG, flags, (int*)nullptr, (u32*)nullptr);
        void* args[] = { (void*)&weakG, (void*)&edgeG, (void*)&flags, (void*)&out };
        hipLaunchCooperativeKernel((void*)canny_hyst, dim3(256), dim3(256), args, 0, stream);
    }
}

// Round 4
// 168.060 us; speedup vs baseline: 2.5801x; 2.5359x over previous
//
#include <hip/hip_runtime.h>
#include <hip/hip_cooperative_groups.h>

namespace cg = cooperative_groups;

#define HH 2048
#define WW 2048
#define WPR 32            // 64-bit words per image row
#define NPIX (HH * WW)
#define NWORDS (HH * WPR)

typedef unsigned long long u64;
typedef unsigned int u32;

// ---------------- global union-find (ECL-CC style, lock-free) ----------------
// Invariant: f[i] <= i (links point to smaller indices) -> acyclic.
__device__ inline int findRoot(int* __restrict__ f, int i) {
    int p = __hip_atomic_load(&f[i], __ATOMIC_RELAXED, __HIP_MEMORY_SCOPE_AGENT);
    while (p != i) {
        int gp = __hip_atomic_load(&f[p], __ATOMIC_RELAXED, __HIP_MEMORY_SCOPE_AGENT);
        if (gp != p)
            __hip_atomic_store(&f[i], gp, __ATOMIC_RELAXED, __HIP_MEMORY_SCOPE_AGENT);
        i = p; p = gp;
    }
    return i;
}

__device__ inline void unite(int* __restrict__ f, int a, int b) {
    int ra = findRoot(f, a), rb = findRoot(f, b);
    while (ra != rb) {
        if (ra > rb) { int t = ra; ra = rb; rb = t; }
        int old = atomicCAS(&f[rb], rb, ra);
        if (old == rb || old == ra) return;
        rb = findRoot(f, old);   // fresh value -> guaranteed progress
    }
}

// ---------------- LDS-local union-find ----------------
__device__ inline int findRootL(int* fl, int i) {
    int p = fl[i];
    while (p != i) {
        int gp = fl[p];
        if (gp != p) fl[i] = gp;   // halving; benign race (any ancestor is valid)
        i = p; p = gp;
    }
    return i;
}

__device__ inline void uniteL(int* fl, int a, int b) {
    int ra = findRootL(fl, a), rb = findRootL(fl, b);
    while (ra != rb) {
        if (ra > rb) { int t = ra; ra = rb; rb = t; }
        int old = atomicCAS(&fl[rb], rb, ra);
        if (old == rb || old == ra) return;
        rb = findRootL(fl, old);
    }
}

// ---------------- Kernel 1: quantize + Sobel + NMS + double threshold ----------------
__global__ __launch_bounds__(256) void canny_prep(
    const float* __restrict__ x, u64* __restrict__ weakG,
    u64* __restrict__ strongG, unsigned int* __restrict__ flags)
{
    __shared__ int imgS[20][68];  // img tile + halo 2 (replicate-clamped)
    __shared__ int magS[18][68];  // |gx|+|gy| tile + halo 1
    const int tid = threadIdx.x;
    const int tx0 = blockIdx.x * 64;
    const int ty0 = blockIdx.y * 16;

    if (flags && blockIdx.x == 0 && blockIdx.y == 0 && tid < 2) flags[tid] = 0u;

    for (int idx = tid; idx < 20 * 68; idx += 256) {
        int r = idx / 68, c = idx - r * 68;
        int gy = ty0 - 2 + r; gy = gy < 0 ? 0 : (gy > HH - 1 ? HH - 1 : gy);
        int gx = tx0 - 2 + c; gx = gx < 0 ? 0 : (gx > WW - 1 ? WW - 1 : gx);
        float v = floorf(x[gy * WW + gx] * 255.0f);
        v = fminf(fmaxf(v, 0.0f), 255.0f);
        imgS[r][c] = (int)v;
    }
    __syncthreads();

    for (int idx = tid; idx < 18 * 66; idx += 256) {
        int r = idx / 66, c = idx - r * 66;
        int a00 = imgS[r][c],     a01 = imgS[r][c + 1],     a02 = imgS[r][c + 2];
        int a10 = imgS[r + 1][c],                           a12 = imgS[r + 1][c + 2];
        int a20 = imgS[r + 2][c], a21 = imgS[r + 2][c + 1], a22 = imgS[r + 2][c + 2];
        int gxv = (a02 + 2 * a12 + a22) - (a00 + 2 * a10 + a20);
        int gyv = (a20 + 2 * a21 + a22) - (a00 + 2 * a01 + a02);
        magS[r][c] = abs(gxv) + abs(gyv);
    }
    __syncthreads();

    const int lane = tid & 63;
    const int wv = tid >> 6;
    for (int i = 0; i < 4; ++i) {
        int rr = wv * 4 + i;
        int gyp = ty0 + rr;
        int r = rr + 1, c = lane + 1;
        int a00 = imgS[rr + 1][lane + 1], a01 = imgS[rr + 1][lane + 2], a02 = imgS[rr + 1][lane + 3];
        int a10 = imgS[rr + 2][lane + 1],                               a12 = imgS[rr + 2][lane + 3];
        int a20 = imgS[rr + 3][lane + 1], a21 = imgS[rr + 3][lane + 2], a22 = imgS[rr + 3][lane + 3];
        int gxv = (a02 + 2 * a12 + a22) - (a00 + 2 * a10 + a20);
        int gyv = (a20 + 2 * a21 + a22) - (a00 + 2 * a01 + a02);
        int mag = magS[r][c];

        // exact direction class via tan(22.5)=sqrt2-1, tan(67.5)=sqrt2+1
        int ay = gyv, ax = gxv;
        if (ay < 0) { ay = -ay; ax = -ax; }
        int cls;
        if (ay == 0) cls = 0;
        else if (ax > 0) {
            long long s = ay + ax, q = 2LL * ax * ax;
            if (s * s < q) cls = 0;
            else { long long t = ay - ax; cls = (t < 0 || t * t < q) ? 1 : 2; }
        } else if (ax == 0) cls = 2;
        else {
            long long h = -(long long)ax, s = ay + h, q = 2LL * h * h;
            if (s * s < q) cls = 0;
            else { long long t = ay - h; cls = (t > 0 && t * t > q) ? 2 : 3; }
        }
        int n1, n2;
        if (cls == 0)      { n1 = magS[r][c + 1];     n2 = magS[r][c - 1]; }
        else if (cls == 1) { n1 = magS[r - 1][c + 1]; n2 = magS[r + 1][c - 1]; }
        else if (cls == 2) { n1 = magS[r - 1][c];     n2 = magS[r + 1][c]; }
        else               { n1 = magS[r - 1][c - 1]; n2 = magS[r + 1][c + 1]; }

        bool keep = (mag >= n1) && (mag > n2) && (gyp > 0) && (gyp < HH - 1);
        bool weak = keep && (mag > 100);
        bool strong = keep && (mag > 200);
        u64 ww = __ballot(weak);
        u64 sw = __ballot(strong);
        if (lane == 0) {
            u64 m = ~0ull;
            if (tx0 == 0) m &= ~1ull;
            if (tx0 + 64 == WW) m &= ~(1ull << 63);
            int widx = gyp * WPR + (tx0 >> 6);
            weakG[widx] = ww & m;
            strongG[widx] = sw & m;
        }
    }
}

// ---------------- Kernel 2: per-tile (64x64) LDS union-find + compressed write-out ----
// Strong-containing local components link DIRECTLY to virtual node 0
// (pixel (0,0) is border -> never weak -> index 0 is free as a super-root).
__global__ __launch_bounds__(256) void canny_local(
    const u64* __restrict__ weakG, const u64* __restrict__ strongG, int* __restrict__ f)
{
    __shared__ int fl[4096];
    __shared__ u64 wRow[64];
    __shared__ u64 sRow[64];
    __shared__ unsigned char hasS[4096];
    const int tid = threadIdx.x;
    const int tileX = blockIdx.x;   // word column 0..31
    const int y0 = blockIdx.y * 64; // tile top row

    if (tid < 64) {
        wRow[tid] = weakG[(y0 + tid) * WPR + tileX];
        sRow[tid] = strongG[(y0 + tid) * WPR + tileX];
    }
    for (int i = tid; i < 4096; i += 256) { fl[i] = i; hasS[i] = 0; }
    __syncthreads();

    // unions: thread -> (row r, 16-bit quarter q); edges to left/up-left/up/up-right
    {
        const int r = tid >> 2, q = tid & 3;
        const u64 qmask = 0xFFFFull << (q * 16);
        const u64 w = wRow[r];
        const u64 above = r ? wRow[r - 1] : 0;
        const int base = r * 64;
        u64 m;
        m = (w & (w >> 1)) & qmask;      // horizontal (b, b+1)
        while (m) { int b = __builtin_ctzll(m); m &= m - 1; uniteL(fl, base + b, base + b + 1); }
        m = (w & above) & qmask;         // up
        while (m) { int b = __builtin_ctzll(m); m &= m - 1; uniteL(fl, base + b, base - 64 + b); }
        m = (w & (above << 1)) & qmask;  // up-left
        while (m) { int b = __builtin_ctzll(m); m &= m - 1; uniteL(fl, base + b, base - 64 + b - 1); }
        m = (w & (above >> 1)) & qmask;  // up-right
        while (m) { int b = __builtin_ctzll(m); m &= m - 1; uniteL(fl, base + b, base - 64 + b + 1); }
    }
    __syncthreads();

    // mark strong-containing local components at their (final) local root
    {
        const int r = tid >> 2, q = tid & 3;
        u64 s = sRow[r] & (0xFFFFull << (q * 16));
        while (s) {
            int b = __builtin_ctzll(s); s &= s - 1;
            hasS[findRootL(fl, r * 64 + b)] = 1;
        }
    }
    __syncthreads();

    // write-out: full local path compression; strong comps -> 0; non-weak -> identity
    for (int k = 0; k < 16; ++k) {
        int i = k * 256 + tid;             // local pixel, consecutive -> coalesced
        int rr = i >> 6, cc = i & 63;
        int g = (y0 + rr) * WW + tileX * 64 + cc;
        int val;
        if ((wRow[rr] >> cc) & 1ull) {
            int rt = findRootL(fl, i);
            val = hasS[rt] ? 0 : (y0 + (rt >> 6)) * WW + tileX * 64 + (rt & 63);
        } else {
            val = g;
        }
        f[g] = val;
    }
}

// ---------------- Kernel 3: cross-tile boundary unions only (~100K, cheap) ----------
__global__ __launch_bounds__(256) void canny_boundary(
    const u64* __restrict__ weakG, int* __restrict__ f)
{
    int t = blockIdx.x * 256 + threadIdx.x;
    if (t < 65536) {
        // (a) cross-word edges (vertical tile boundaries), all rows
        int y = t >> 5, c = t & 31;
        if (c == 31) return;
        u64 w0 = weakG[y * WPR + c];
        u64 w1 = weakG[y * WPR + c + 1];
        int p63 = y * WW + c * 64 + 63;
        int p64 = y * WW + c * 64 + 64;
        if ((w0 >> 63) & w1 & 1ull) unite(f, p63, p64);
        if (y < HH - 1) {
            u64 w0d = weakG[(y + 1) * WPR + c];
            u64 w1d = weakG[(y + 1) * WPR + c + 1];
            if ((w0 >> 63) & w1d & 1ull) unite(f, p63, p64 + WW);       // down-right
            if ((w1 & 1ull) & (w0d >> 63)) unite(f, p64, p63 + WW);     // down-left
        }
    } else {
        // (b) horizontal tile-boundary rows (y % 64 == 63), within-word edges only
        int idx = t - 65536;
        if (idx >= 31 * 32) return;
        int y = 63 + (idx >> 5) * 64;
        int c = idx & 31;
        u64 w = weakG[y * WPR + c];
        u64 below = weakG[(y + 1) * WPR + c];
        int base = y * WW + c * 64;
        u64 m;
        m = w & below;            // down
        while (m) { int b = __builtin_ctzll(m); m &= m - 1; unite(f, base + b, base + b + WW); }
        m = w & (below << 1);     // down-left (within word)
        while (m) { int b = __builtin_ctzll(m); m &= m - 1; unite(f, base + b, base + b + WW - 1); }
        m = w & (below >> 1);     // down-right (within word)
        while (m) { int b = __builtin_ctzll(m); m &= m - 1; unite(f, base + b, base + b + WW + 1); }
    }
}

// ---------------- Kernel 4: edge query (root==0) fused with 3-channel fp32 write ----
__global__ __launch_bounds__(256) void canny_edgefuse(
    const u64* __restrict__ weakG, int* __restrict__ f, float* __restrict__ out)
{
    int u = blockIdx.x * 256 + threadIdx.x;   // 0..262143, 16 px each
    int px = u << 4;
    u64 w = weakG[px >> 6];
    u32 bits = (u32)(w >> (px & 63)) & 0xFFFFu;
    u32 e = 0;
    u32 m = bits;
    while (m) {
        int b = __builtin_ctz(m); m &= m - 1;
        if (findRoot(f, px + b) == 0) e |= 1u << b;
    }
    float4 v[4];
    #pragma unroll
    for (int q = 0; q < 4; ++q) {
        v[q].x = (float)((e >> (q * 4 + 0)) & 1u);
        v[q].y = (float)((e >> (q * 4 + 1)) & 1u);
        v[q].z = (float)((e >> (q * 4 + 2)) & 1u);
        v[q].w = (float)((e >> (q * 4 + 3)) & 1u);
    }
    #pragma unroll
    for (int ch = 0; ch < 3; ++ch) {
        float4* p = reinterpret_cast<float4*>(out + (size_t)ch * NPIX + px);
        p[0] = v[0]; p[1] = v[1]; p[2] = v[2]; p[3] = v[3];
    }
}

// ---------------- Fallback (small ws): proven cooperative hysteresis ----------------
__global__ __launch_bounds__(256) void canny_hyst(
    const u64* __restrict__ weakG, u64* __restrict__ edgeG,
    unsigned int* __restrict__ flags, float* __restrict__ out)
{
    cg::grid_group grid = cg::this_grid();
    const int tid = threadIdx.x;
    const int b = blockIdx.x;
    const int r = tid >> 5;
    const int c = tid & 31;
    const int row0 = b * 8;
    __shared__ u64 weakL[8][32];
    __shared__ u64 edgeL[10][32];
    __shared__ int sChg[2];
    __shared__ int sAny;

    weakL[r][c] = weakG[(row0 + r) * WPR + c];
    edgeL[r + 1][c] = edgeG[(row0 + r) * WPR + c];

    int iter = 0;
    for (;;) {
        if (tid < 32) {
            u64 v = 0;
            if (b > 0) v = __hip_atomic_load(&edgeG[(row0 - 1) * WPR + tid],
                                             __ATOMIC_RELAXED, __HIP_MEMORY_SCOPE_AGENT);
            edgeL[0][tid] = v;
        } else if (tid < 64) {
            int cc = tid - 32;
            u64 v = 0;
            if (b < (int)gridDim.x - 1)
                v = __hip_atomic_load(&edgeG[(row0 + 8) * WPR + cc],
                                      __ATOMIC_RELAXED, __HIP_MEMORY_SCOPE_AGENT);
            edgeL[9][cc] = v;
        }
        if (tid == 0) sAny = 0;
        if (tid < 2) sChg[tid] = 0;
        __syncthreads();

        int p = 0;
        for (;;) {
            u64 up = edgeL[r][c],     upl = c ? edgeL[r][c - 1] : 0,     upr = (c < 31) ? edgeL[r][c + 1] : 0;
            u64 mi = edgeL[r + 1][c], mil = c ? edgeL[r + 1][c - 1] : 0, mir = (c < 31) ? edgeL[r + 1][c + 1] : 0;
            u64 dn = edgeL[r + 2][c], dnl = c ? edgeL[r + 2][c - 1] : 0, dnr = (c < 31) ? edgeL[r + 2][c + 1] : 0;
            u64 A = up | (up << 1) | (up >> 1) | (upl >> 63) | (upr << 63);
            u64 B = mi | (mi << 1) | (mi >> 1) | (mil >> 63) | (mir << 63);
            u64 C = dn | (dn << 1) | (dn >> 1) | (dnl >> 63) | (dnr << 63);
            u64 ne = mi | (weakL[r][c] & (A | B | C));
            bool chg = (ne != mi);
            __syncthreads();
            edgeL[r + 1][c] = ne;
            if (chg) { sChg[p] = 1; sAny = 1; }
            if (tid == 0) sChg[p ^ 1] = 0;
            __syncthreads();
            if (!sChg[p]) break;
            p ^= 1;
        }

        if (sAny) edgeG[(row0 + r) * WPR + c] = edgeL[r + 1][c];
        if (sAny && tid == 0) atomicOr(&flags[iter & 1], 1u);
        __threadfence();
        grid.sync();
        unsigned fl2 = __hip_atomic_load(&flags[iter & 1], __ATOMIC_ACQUIRE, __HIP_MEMORY_SCOPE_AGENT);
        if (tid == 0) flags[(iter + 1) & 1] = 0u;
        __threadfence();
        grid.sync();
        if (fl2 == 0) break;
        ++iter;
    }

    for (int chn = 0; chn < 3; ++chn) {
        for (int rr = 0; rr < 8; ++rr) {
            size_t base2 = ((size_t)chn * HH + (size_t)(row0 + rr)) * WW;
            for (int k = tid; k < 512; k += 256) {
                u64 w = edgeL[rr + 1][k >> 4];
                int sh = (k & 15) * 4;
                float4 v;
                v.x = (float)((w >> sh) & 1ull);
                v.y = (float)((w >> (sh + 1)) & 1ull);
                v.z = (float)((w >> (sh + 2)) & 1ull);
                v.w = (float)((w >> (sh + 3)) & 1ull);
                *reinterpret_cast<float4*>(out + base2 + (size_t)k * 4) = v;
            }
        }
    }
}

extern "C" void kernel_launch(void* const* d_in, const int* in_sizes, int n_in,
                              void* d_out, int out_size, void* d_ws, size_t ws_size,
                              hipStream_t stream) {
    const float* x = (const float*)d_in[0];
    float* out = (float*)d_out;

    const size_t BM = (size_t)NWORDS * 8;          // 512 KB per bitmap
    const size_t need = 2 * BM + (size_t)NPIX * 4; // weak + strong + labels = 17 MB

    if (ws_size >= need) {
        u64* weakG   = (u64*)d_ws;
        u64* strongG = weakG + NWORDS;
        int* f = (int*)(strongG + NWORDS);

        hipLaunchKernelGGL(canny_prep, dim3(WW / 64, HH / 16), dim3(256), 0, stream,
                           x, weakG, strongG, (unsigned int*)nullptr);
        hipLaunchKernelGGL(canny_local, dim3(32, 32), dim3(256), 0, stream,
                           weakG, strongG, f);
        hipLaunchKernelGGL(canny_boundary, dim3((65536 + 31 * 32 + 255) / 256), dim3(256), 0, stream,
                           weakG, f);
        hipLaunchKernelGGL(canny_edgefuse, dim3(NPIX / 16 / 256), dim3(256), 0, stream,
                           weakG, f, out);
    } else {
        u64* edgeG = (u64*)d_ws;
        u64* weakG = edgeG + NWORDS;
        unsigned int* flags = (unsigned int*)(weakG + NWORDS);
        hipLaunchKernelGGL(canny_prep, dim3(WW / 64, HH / 16), dim3(256), 0, stream,
                           x, weakG, edgeG, flags);
        void* args[] = { (void*)&weakG, (void*)&edgeG, (void*)&flags, (void*)&out };
        hipLaunchCooperativeKernel((void*)canny_hyst, dim3(256), dim3(256), args, 0, stream);
    }
}

// Round 5
// 155.114 us; speedup vs baseline: 2.7954x; 1.0835x over previous
//
#include <hip/hip_runtime.h>
#include <hip/hip_cooperative_groups.h>

namespace cg = cooperative_groups;

#define HH 2048
#define WW 2048
#define WPR 32            // 64-bit words per image row
#define NPIX (HH * WW)
#define NWORDS (HH * WPR)

typedef unsigned long long u64;
typedef unsigned int u32;

// ---------------- global union-find (ECL-CC style, lock-free) ----------------
// Invariant: f[i] <= i (links point to smaller indices) -> acyclic.
__device__ inline int findRoot(int* __restrict__ f, int i) {
    int p = __hip_atomic_load(&f[i], __ATOMIC_RELAXED, __HIP_MEMORY_SCOPE_AGENT);
    while (p != i) {
        int gp = __hip_atomic_load(&f[p], __ATOMIC_RELAXED, __HIP_MEMORY_SCOPE_AGENT);
        if (gp != p)
            __hip_atomic_store(&f[i], gp, __ATOMIC_RELAXED, __HIP_MEMORY_SCOPE_AGENT);
        i = p; p = gp;
    }
    return i;
}

__device__ inline void unite(int* __restrict__ f, int a, int b) {
    int ra = findRoot(f, a), rb = findRoot(f, b);
    while (ra != rb) {
        if (ra > rb) { int t = ra; ra = rb; rb = t; }
        int old = atomicCAS(&f[rb], rb, ra);
        if (old == rb || old == ra) return;
        rb = findRoot(f, old);   // fresh value -> guaranteed progress
    }
}

// read-only root chase (no halving writes) — trees are shallow post-compression
__device__ inline int findRootRO(const int* __restrict__ f, int i) {
    int p = __hip_atomic_load(&f[i], __ATOMIC_RELAXED, __HIP_MEMORY_SCOPE_AGENT);
    while (true) {
        int gp = __hip_atomic_load(&f[p], __ATOMIC_RELAXED, __HIP_MEMORY_SCOPE_AGENT);
        if (gp == p) return p;
        p = gp;
    }
}

// ---------------- LDS-local union-find ----------------
__device__ inline int findRootL(int* fl, int i) {
    int p = fl[i];
    while (p != i) {
        int gp = fl[p];
        if (gp != p) fl[i] = gp;   // halving; benign race
        i = p; p = gp;
    }
    return i;
}

__device__ inline void uniteL(int* fl, int a, int b) {
    int ra = findRootL(fl, a), rb = findRootL(fl, b);
    while (ra != rb) {
        if (ra > rb) { int t = ra; ra = rb; rb = t; }
        int old = atomicCAS(&fl[rb], rb, ra);
        if (old == rb || old == ra) return;
        rb = findRootL(fl, old);
    }
}

// ---------------- Kernel 1 (fused): quantize+Sobel+NMS+thresholds+LOCAL CC ----------
// 64x64 tile per block. Strong-containing local components link to virtual node 0
// (pixel (0,0) is border -> never weak -> index 0 free as super-root).
__global__ __launch_bounds__(256) void canny_tile(
    const float* __restrict__ x, u64* __restrict__ weakG,
    u64* __restrict__ strongG, int* __restrict__ f)
{
    __shared__ int imgS[68 * 68];       // quantized img, halo 2
    __shared__ int magS[66 * 66];       // |gx|+|gy|, halo 1; REUSED as fl[4096]
    __shared__ u64 wRow[64], sRow[64];
    __shared__ unsigned char hasS[4096];
    int* fl = magS;                     // alias (4356 >= 4096), phases disjoint

    const int tid = threadIdx.x;
    const int x0 = blockIdx.x * 64;
    const int y0 = blockIdx.y * 64;

    // stage 68x68 quantized image (exact fp32 floor(x*255) clip), replicate border
    for (int idx = tid; idx < 68 * 68; idx += 256) {
        int r = idx / 68, c = idx - r * 68;
        int gy = y0 - 2 + r; gy = gy < 0 ? 0 : (gy > HH - 1 ? HH - 1 : gy);
        int gx = x0 - 2 + c; gx = gx < 0 ? 0 : (gx > WW - 1 ? WW - 1 : gx);
        float v = floorf(x[gy * WW + gx] * 255.0f);
        v = fminf(fmaxf(v, 0.0f), 255.0f);
        imgS[idx] = (int)v;
    }
    __syncthreads();

    // L1 gradient magnitude for 66x66 (halo 1), integer exact
    for (int idx = tid; idx < 66 * 66; idx += 256) {
        int r = idx / 66, c = idx - r * 66;
        int i0 = r * 68 + c;
        int a00 = imgS[i0],       a01 = imgS[i0 + 1],   a02 = imgS[i0 + 2];
        int a10 = imgS[i0 + 68],                        a12 = imgS[i0 + 70];
        int a20 = imgS[i0 + 136], a21 = imgS[i0 + 137], a22 = imgS[i0 + 138];
        int gxv = (a02 + 2 * a12 + a22) - (a00 + 2 * a10 + a20);
        int gyv = (a20 + 2 * a21 + a22) - (a00 + 2 * a01 + a02);
        magS[idx] = abs(gxv) + abs(gyv);
    }
    __syncthreads();

    // NMS + thresholds: wave wv handles contiguous 16-row band
    const int lane = tid & 63;
    const int wv = tid >> 6;
    for (int i = 0; i < 16; ++i) {
        int rr = wv * 16 + i;
        int gyp = y0 + rr;
        int ic = (rr + 2) * 68 + lane + 2;  // img center
        int mc = (rr + 1) * 66 + lane + 1;  // mag center
        int a00 = imgS[ic - 69], a01 = imgS[ic - 68], a02 = imgS[ic - 67];
        int a10 = imgS[ic - 1],                       a12 = imgS[ic + 1];
        int a20 = imgS[ic + 67], a21 = imgS[ic + 68], a22 = imgS[ic + 69];
        int gxv = (a02 + 2 * a12 + a22) - (a00 + 2 * a10 + a20);
        int gyv = (a20 + 2 * a21 + a22) - (a00 + 2 * a01 + a02);
        int mag = magS[mc];

        // exact direction class via tan(22.5)=sqrt2-1, tan(67.5)=sqrt2+1 (int squares)
        int ay = gyv, ax = gxv;
        if (ay < 0) { ay = -ay; ax = -ax; }
        int cls;
        if (ay == 0) cls = 0;
        else if (ax > 0) {
            long long s = ay + ax, q = 2LL * ax * ax;
            if (s * s < q) cls = 0;
            else { long long t = ay - ax; cls = (t < 0 || t * t < q) ? 1 : 2; }
        } else if (ax == 0) cls = 2;
        else {
            long long h = -(long long)ax, s = ay + h, q = 2LL * h * h;
            if (s * s < q) cls = 0;
            else { long long t = ay - h; cls = (t > 0 && t * t > q) ? 2 : 3; }
        }
        int n1, n2;
        if (cls == 0)      { n1 = magS[mc + 1];  n2 = magS[mc - 1]; }
        else if (cls == 1) { n1 = magS[mc - 65]; n2 = magS[mc + 65]; }
        else if (cls == 2) { n1 = magS[mc - 66]; n2 = magS[mc + 66]; }
        else               { n1 = magS[mc - 67]; n2 = magS[mc + 67]; }

        bool keep = (mag >= n1) && (mag > n2) && (gyp > 0) && (gyp < HH - 1);
        bool weak = keep && (mag > 100);
        bool strong = keep && (mag > 200);
        u64 ww = __ballot(weak);
        u64 sw = __ballot(strong);
        if (lane == 0) {
            u64 m = ~0ull;
            if (x0 == 0) m &= ~1ull;
            if (x0 + 64 == WW) m &= ~(1ull << 63);
            wRow[rr] = ww & m;
            sRow[rr] = sw & m;
        }
    }
    __syncthreads();   // magS no longer read; safe to alias as fl

    for (int i = tid; i < 4096; i += 256) { fl[i] = i; hasS[i] = 0; }
    __syncthreads();

    // local unions: thread -> (row r, 16-bit quarter q); left/up-left/up/up-right
    {
        const int r = tid >> 2, q = tid & 3;
        const u64 qmask = 0xFFFFull << (q * 16);
        const u64 w = wRow[r];
        const u64 above = r ? wRow[r - 1] : 0;
        const int base = r * 64;
        u64 m;
        m = (w & (w >> 1)) & qmask;
        while (m) { int b = __builtin_ctzll(m); m &= m - 1; uniteL(fl, base + b, base + b + 1); }
        m = (w & above) & qmask;
        while (m) { int b = __builtin_ctzll(m); m &= m - 1; uniteL(fl, base + b, base - 64 + b); }
        m = (w & (above << 1)) & qmask;
        while (m) { int b = __builtin_ctzll(m); m &= m - 1; uniteL(fl, base + b, base - 64 + b - 1); }
        m = (w & (above >> 1)) & qmask;
        while (m) { int b = __builtin_ctzll(m); m &= m - 1; uniteL(fl, base + b, base - 64 + b + 1); }
    }
    __syncthreads();

    // mark strong-containing local components at their final local root
    {
        const int r = tid >> 2, q = tid & 3;
        u64 s = sRow[r] & (0xFFFFull << (q * 16));
        while (s) {
            int b = __builtin_ctzll(s); s &= s - 1;
            hasS[findRootL(fl, r * 64 + b)] = 1;
        }
    }
    __syncthreads();

    // write-out: full local compression; strong comps -> 0; non-weak -> identity
    for (int k = 0; k < 16; ++k) {
        int i = k * 256 + tid;
        int rr = i >> 6, cc = i & 63;
        int g = (y0 + rr) * WW + x0 + cc;
        int val = g;
        if ((wRow[rr] >> cc) & 1ull) {
            int rt = findRootL(fl, i);
            val = hasS[rt] ? 0 : (y0 + (rt >> 6)) * WW + x0 + (rt & 63);
        }
        f[g] = val;
    }
    if (tid < 64) {
        weakG[(y0 + tid) * WPR + blockIdx.x] = wRow[tid];
        strongG[(y0 + tid) * WPR + blockIdx.x] = sRow[tid];
    }
}

// ---------------- Kernel 2: cross-tile boundary unions, 1 thread per boundary px ----
__global__ __launch_bounds__(256) void canny_boundary(
    const u64* __restrict__ weakG, int* __restrict__ f)
{
    int t = blockIdx.x * 256 + threadIdx.x;
    if (t < 65536) {
        // (a) vertical word boundaries: word pair (c, c+1), all rows
        int y = t >> 5, c = t & 31;
        if (c == 31) return;
        u64 w0 = weakG[y * WPR + c];
        u64 w1 = weakG[y * WPR + c + 1];
        int a = (int)(w0 >> 63) & 1, b = (int)w1 & 1;
        if (!(a | b)) return;
        int p63 = y * WW + c * 64 + 63;
        int p64 = p63 + 1;
        if (a & b) unite(f, p63, p64);
        if (y < HH - 1) {
            u64 w0d = weakG[(y + 1) * WPR + c];
            u64 w1d = weakG[(y + 1) * WPR + c + 1];
            if (a && (w1d & 1ull)) unite(f, p63, p64 + WW);
            if (b && (w0d >> 63)) unite(f, p64, p63 + WW);
        }
    } else {
        // (b) horizontal tile boundaries: one thread per pixel on rows y=63,127,...
        int idx = t - 65536;
        if (idx >= 31 * 2048) return;
        int y = 63 + (idx >> 11) * 64;
        int xx = idx & 2047;
        u64 w = weakG[y * WPR + (xx >> 6)];
        if (!((w >> (xx & 63)) & 1ull)) return;
        int p = y * WW + xx;
        u64 wd = weakG[(y + 1) * WPR + (xx >> 6)];
        if ((wd >> (xx & 63)) & 1ull) unite(f, p, p + WW);
        if (xx > 0) {
            u64 wl = weakG[(y + 1) * WPR + ((xx - 1) >> 6)];
            if ((wl >> ((xx - 1) & 63)) & 1ull) unite(f, p, p + WW - 1);
        }
        if (xx < WW - 1) {
            u64 wr = weakG[(y + 1) * WPR + ((xx + 1) >> 6)];
            if ((wr >> ((xx + 1) & 63)) & 1ull) unite(f, p, p + WW + 1);
        }
    }
}

// ---------------- Kernel 3: edge query (root==0) fused with coalesced 3ch write ----
__global__ __launch_bounds__(256) void canny_edgefuse(
    const u64* __restrict__ weakG, const int* __restrict__ f, float* __restrict__ out)
{
    __shared__ unsigned short eS[256];
    const int tid = threadIdx.x;
    const int B = blockIdx.x * 4096;          // px segment base
    int px0 = B + tid * 16;
    u64 w = weakG[px0 >> 6];
    u32 bits = (u32)(w >> (px0 & 63)) & 0xFFFFu;
    u32 e = 0;
    int lastp = -1, laste = 0;
    u32 m = bits;
    while (m) {
        int b = __builtin_ctz(m); m &= m - 1;
        int p = __hip_atomic_load(&f[px0 + b], __ATOMIC_RELAXED, __HIP_MEMORY_SCOPE_AGENT);
        int ed;
        if (p == 0) ed = 1;
        else if (p == lastp) ed = laste;
        else { ed = (findRootRO(f, p) == 0); lastp = p; laste = ed; }
        e |= (u32)ed << b;
    }
    eS[tid] = (unsigned short)e;
    __syncthreads();

    #pragma unroll
    for (int ch = 0; ch < 3; ++ch) {
        #pragma unroll
        for (int j = 0; j < 4; ++j) {
            int idx = j * 256 + tid;              // float4 index within segment
            u32 eb = (u32)(eS[idx >> 2] >> ((idx & 3) * 4)) & 0xFu;
            float4 v;
            v.x = (float)(eb & 1u);
            v.y = (float)((eb >> 1) & 1u);
            v.z = (float)((eb >> 2) & 1u);
            v.w = (float)((eb >> 3) & 1u);
            *reinterpret_cast<float4*>(out + (size_t)ch * NPIX + B + idx * 4) = v;
        }
    }
}

// ---------------- Fallback path (small ws): prep + proven cooperative hysteresis ----
__global__ __launch_bounds__(256) void canny_prep(
    const float* __restrict__ x, u64* __restrict__ weakG,
    u64* __restrict__ strongG, unsigned int* __restrict__ flags)
{
    __shared__ int imgS[20][68];
    __shared__ int magS[18][68];
    const int tid = threadIdx.x;
    const int tx0 = blockIdx.x * 64;
    const int ty0 = blockIdx.y * 16;

    if (flags && blockIdx.x == 0 && blockIdx.y == 0 && tid < 2) flags[tid] = 0u;

    for (int idx = tid; idx < 20 * 68; idx += 256) {
        int r = idx / 68, c = idx - r * 68;
        int gy = ty0 - 2 + r; gy = gy < 0 ? 0 : (gy > HH - 1 ? HH - 1 : gy);
        int gx = tx0 - 2 + c; gx = gx < 0 ? 0 : (gx > WW - 1 ? WW - 1 : gx);
        float v = floorf(x[gy * WW + gx] * 255.0f);
        v = fminf(fmaxf(v, 0.0f), 255.0f);
        imgS[r][c] = (int)v;
    }
    __syncthreads();

    for (int idx = tid; idx < 18 * 66; idx += 256) {
        int r = idx / 66, c = idx - r * 66;
        int a00 = imgS[r][c],     a01 = imgS[r][c + 1],     a02 = imgS[r][c + 2];
        int a10 = imgS[r + 1][c],                           a12 = imgS[r + 1][c + 2];
        int a20 = imgS[r + 2][c], a21 = imgS[r + 2][c + 1], a22 = imgS[r + 2][c + 2];
        int gxv = (a02 + 2 * a12 + a22) - (a00 + 2 * a10 + a20);
        int gyv = (a20 + 2 * a21 + a22) - (a00 + 2 * a01 + a02);
        magS[r][c] = abs(gxv) + abs(gyv);
    }
    __syncthreads();

    const int lane = tid & 63;
    const int wv = tid >> 6;
    for (int i = 0; i < 4; ++i) {
        int rr = wv * 4 + i;
        int gyp = ty0 + rr;
        int r = rr + 1, c = lane + 1;
        int a00 = imgS[rr + 1][lane + 1], a01 = imgS[rr + 1][lane + 2], a02 = imgS[rr + 1][lane + 3];
        int a10 = imgS[rr + 2][lane + 1],                               a12 = imgS[rr + 2][lane + 3];
        int a20 = imgS[rr + 3][lane + 1], a21 = imgS[rr + 3][lane + 2], a22 = imgS[rr + 3][lane + 3];
        int gxv = (a02 + 2 * a12 + a22) - (a00 + 2 * a10 + a20);
        int gyv = (a20 + 2 * a21 + a22) - (a00 + 2 * a01 + a02);
        int mag = magS[r][c];

        int ay = gyv, ax = gxv;
        if (ay < 0) { ay = -ay; ax = -ax; }
        int cls;
        if (ay == 0) cls = 0;
        else if (ax > 0) {
            long long s = ay + ax, q = 2LL * ax * ax;
            if (s * s < q) cls = 0;
            else { long long t = ay - ax; cls = (t < 0 || t * t < q) ? 1 : 2; }
        } else if (ax == 0) cls = 2;
        else {
            long long h = -(long long)ax, s = ay + h, q = 2LL * h * h;
            if (s * s < q) cls = 0;
            else { long long t = ay - h; cls = (t > 0 && t * t > q) ? 2 : 3; }
        }
        int n1, n2;
        if (cls == 0)      { n1 = magS[r][c + 1];     n2 = magS[r][c - 1]; }
        else if (cls == 1) { n1 = magS[r - 1][c + 1]; n2 = magS[r + 1][c - 1]; }
        else if (cls == 2) { n1 = magS[r - 1][c];     n2 = magS[r + 1][c]; }
        else               { n1 = magS[r - 1][c - 1]; n2 = magS[r + 1][c + 1]; }

        bool keep = (mag >= n1) && (mag > n2) && (gyp > 0) && (gyp < HH - 1);
        bool weak = keep && (mag > 100);
        bool strong = keep && (mag > 200);
        u64 ww = __ballot(weak);
        u64 sw = __ballot(strong);
        if (lane == 0) {
            u64 mm = ~0ull;
            if (tx0 == 0) mm &= ~1ull;
            if (tx0 + 64 == WW) mm &= ~(1ull << 63);
            int widx = gyp * WPR + (tx0 >> 6);
            weakG[widx] = ww & mm;
            strongG[widx] = sw & mm;
        }
    }
}

__global__ __launch_bounds__(256) void canny_hyst(
    const u64* __restrict__ weakG, u64* __restrict__ edgeG,
    unsigned int* __restrict__ flags, float* __restrict__ out)
{
    cg::grid_group grid = cg::this_grid();
    const int tid = threadIdx.x;
    const int b = blockIdx.x;
    const int r = tid >> 5;
    const int c = tid & 31;
    const int row0 = b * 8;
    __shared__ u64 weakL[8][32];
    __shared__ u64 edgeL[10][32];
    __shared__ int sChg[2];
    __shared__ int sAny;

    weakL[r][c] = weakG[(row0 + r) * WPR + c];
    edgeL[r + 1][c] = edgeG[(row0 + r) * WPR + c];

    int iter = 0;
    for (;;) {
        if (tid < 32) {
            u64 v = 0;
            if (b > 0) v = __hip_atomic_load(&edgeG[(row0 - 1) * WPR + tid],
                                             __ATOMIC_RELAXED, __HIP_MEMORY_SCOPE_AGENT);
            edgeL[0][tid] = v;
        } else if (tid < 64) {
            int cc = tid - 32;
            u64 v = 0;
            if (b < (int)gridDim.x - 1)
                v = __hip_atomic_load(&edgeG[(row0 + 8) * WPR + cc],
                                      __ATOMIC_RELAXED, __HIP_MEMORY_SCOPE_AGENT);
            edgeL[9][cc] = v;
        }
        if (tid == 0) sAny = 0;
        if (tid < 2) sChg[tid] = 0;
        __syncthreads();

        int p = 0;
        for (;;) {
            u64 up = edgeL[r][c],     upl = c ? edgeL[r][c - 1] : 0,     upr = (c < 31) ? edgeL[r][c + 1] : 0;
            u64 mi = edgeL[r + 1][c], mil = c ? edgeL[r + 1][c - 1] : 0, mir = (c < 31) ? edgeL[r + 1][c + 1] : 0;
            u64 dn = edgeL[r + 2][c], dnl = c ? edgeL[r + 2][c - 1] : 0, dnr = (c < 31) ? edgeL[r + 2][c + 1] : 0;
            u64 A = up | (up << 1) | (up >> 1) | (upl >> 63) | (upr << 63);
            u64 B = mi | (mi << 1) | (mi >> 1) | (mil >> 63) | (mir << 63);
            u64 C = dn | (dn << 1) | (dn >> 1) | (dnl >> 63) | (dnr << 63);
            u64 ne = mi | (weakL[r][c] & (A | B | C));
            bool chg = (ne != mi);
            __syncthreads();
            edgeL[r + 1][c] = ne;
            if (chg) { sChg[p] = 1; sAny = 1; }
            if (tid == 0) sChg[p ^ 1] = 0;
            __syncthreads();
            if (!sChg[p]) break;
            p ^= 1;
        }

        if (sAny) edgeG[(row0 + r) * WPR + c] = edgeL[r + 1][c];
        if (sAny && tid == 0) atomicOr(&flags[iter & 1], 1u);
        __threadfence();
        grid.sync();
        unsigned fl2 = __hip_atomic_load(&flags[iter & 1], __ATOMIC_ACQUIRE, __HIP_MEMORY_SCOPE_AGENT);
        if (tid == 0) flags[(iter + 1) & 1] = 0u;
        __threadfence();
        grid.sync();
        if (fl2 == 0) break;
        ++iter;
    }

    for (int chn = 0; chn < 3; ++chn) {
        for (int rr = 0; rr < 8; ++rr) {
            size_t base2 = ((size_t)chn * HH + (size_t)(row0 + rr)) * WW;
            for (int k = tid; k < 512; k += 256) {
                u64 w = edgeL[rr + 1][k >> 4];
                int sh = (k & 15) * 4;
                float4 v;
                v.x = (float)((w >> sh) & 1ull);
                v.y = (float)((w >> (sh + 1)) & 1ull);
                v.z = (float)((w >> (sh + 2)) & 1ull);
                v.w = (float)((w >> (sh + 3)) & 1ull);
                *reinterpret_cast<float4*>(out + base2 + (size_t)k * 4) = v;
            }
        }
    }
}

extern "C" void kernel_launch(void* const* d_in, const int* in_sizes, int n_in,
                              void* d_out, int out_size, void* d_ws, size_t ws_size,
                              hipStream_t stream) {
    const float* x = (const float*)d_in[0];
    float* out = (float*)d_out;

    const size_t BM = (size_t)NWORDS * 8;          // 512 KB per bitmap
    const size_t need = 2 * BM + (size_t)NPIX * 4; // weak + strong + labels = 17 MB

    if (ws_size >= need) {
        u64* weakG   = (u64*)d_ws;
        u64* strongG = weakG + NWORDS;
        int* f = (int*)(strongG + NWORDS);

        hipLaunchKernelGGL(canny_tile, dim3(32, 32), dim3(256), 0, stream,
                           x, weakG, strongG, f);
        hipLaunchKernelGGL(canny_boundary, dim3((65536 + 31 * 2048 + 255) / 256), dim3(256),
                           0, stream, weakG, f);
        hipLaunchKernelGGL(canny_edgefuse, dim3(NPIX / 4096), dim3(256), 0, stream,
                           weakG, f, out);
    } else {
        u64* edgeG = (u64*)d_ws;
        u64* weakG = edgeG + NWORDS;
        unsigned int* flags = (unsigned int*)(weakG + NWORDS);
        hipLaunchKernelGGL(canny_prep, dim3(WW / 64, HH / 16), dim3(256), 0, stream,
                           x, weakG, edgeG, flags);
        void* args[] = { (void*)&weakG, (void*)&edgeG, (void*)&flags, (void*)&out };
        hipLaunchCooperativeKernel((void*)canny_hyst, dim3(256), dim3(256), args, 0, stream);
    }
}

// Round 6
// 127.763 us; speedup vs baseline: 3.3939x; 1.2141x over previous
//
#include <hip/hip_runtime.h>
#include <hip/hip_cooperative_groups.h>

namespace cg = cooperative_groups;

#define HH 2048
#define WW 2048
#define WPR 32            // 64-bit words per image row
#define NPIX (HH * WW)
#define NWORDS (HH * WPR)

typedef unsigned long long u64;
typedef unsigned int u32;

// ---------------- global union-find (ECL-CC style, lock-free) ----------------
// Invariant: f[i] <= i (links point to smaller indices) -> acyclic.
__device__ inline int findRoot(int* __restrict__ f, int i) {
    int p = __hip_atomic_load(&f[i], __ATOMIC_RELAXED, __HIP_MEMORY_SCOPE_AGENT);
    while (p != i) {
        int gp = __hip_atomic_load(&f[p], __ATOMIC_RELAXED, __HIP_MEMORY_SCOPE_AGENT);
        if (gp != p)
            __hip_atomic_store(&f[i], gp, __ATOMIC_RELAXED, __HIP_MEMORY_SCOPE_AGENT);
        i = p; p = gp;
    }
    return i;
}

__device__ inline void unite(int* __restrict__ f, int a, int b) {
    int ra = findRoot(f, a), rb = findRoot(f, b);
    while (ra != rb) {
        if (ra > rb) { int t = ra; ra = rb; rb = t; }
        int old = atomicCAS(&f[rb], rb, ra);
        if (old == rb || old == ra) return;
        rb = findRoot(f, old);   // fresh value -> guaranteed progress
    }
}

// read-only root chase (trees are shallow post-compression)
__device__ inline int findRootRO(const int* __restrict__ f, int i) {
    int p = __hip_atomic_load(&f[i], __ATOMIC_RELAXED, __HIP_MEMORY_SCOPE_AGENT);
    while (true) {
        int gp = __hip_atomic_load(&f[p], __ATOMIC_RELAXED, __HIP_MEMORY_SCOPE_AGENT);
        if (gp == p) return p;
        p = gp;
    }
}

// ---------------- LDS-local union-find ----------------
__device__ inline int findRootL(volatile int* fl, int i) {
    int p = fl[i];
    while (p != i) {
        int gp = fl[p];
        if (gp != p) fl[i] = gp;   // halving; benign race
        i = p; p = gp;
    }
    return i;
}

__device__ inline void uniteL(int* fl, int a, int b) {
    int ra = findRootL(fl, a), rb = findRootL(fl, b);
    while (ra != rb) {
        if (ra > rb) { int t = ra; ra = rb; rb = t; }
        int old = atomicCAS(&fl[rb], rb, ra);
        if (old == rb || old == ra) return;
        rb = findRootL(fl, old);
    }
}

// ---------------- Kernel 1 (fused): quantize+Sobel+NMS+thresholds+LOCAL CC ----------
// 64x64 tile per block, 512 threads. Local node 0 is a VIRTUAL strong super-root
// (pixels are 1..4096). Strong-containing components end at root 0 -> f = 0
// (global pixel 0 is border -> never weak -> global index 0 free as super-root).
__global__ __launch_bounds__(512) void canny_tile(
    const float* __restrict__ x, u64* __restrict__ weakG,
    u64* __restrict__ strongG, int* __restrict__ f)
{
    __shared__ int imgS[68 * 68];            // quantized img, halo 2; REUSED as fl[4097]
    __shared__ unsigned short magS[66 * 66]; // |gx|+|gy| (<=2040), halo 1
    __shared__ u64 wRow[64], sRow[64];
    int* fl = imgS;                          // alias (4624 >= 4097), phases disjoint

    const int tid = threadIdx.x;
    const int x0 = blockIdx.x * 64;
    const int y0 = blockIdx.y * 64;

    // stage 68x68 quantized image (exact fp32 floor(x*255) clip), replicate border
    for (int idx = tid; idx < 68 * 68; idx += 512) {
        int r = idx / 68, c = idx - r * 68;
        int gy = y0 - 2 + r; gy = gy < 0 ? 0 : (gy > HH - 1 ? HH - 1 : gy);
        int gx = x0 - 2 + c; gx = gx < 0 ? 0 : (gx > WW - 1 ? WW - 1 : gx);
        float v = floorf(x[gy * WW + gx] * 255.0f);
        v = fminf(fmaxf(v, 0.0f), 255.0f);
        imgS[idx] = (int)v;
    }
    __syncthreads();

    // L1 gradient magnitude for 66x66 (halo 1), integer exact
    for (int idx = tid; idx < 66 * 66; idx += 512) {
        int r = idx / 66, c = idx - r * 66;
        int i0 = r * 68 + c;
        int a00 = imgS[i0],       a01 = imgS[i0 + 1],   a02 = imgS[i0 + 2];
        int a10 = imgS[i0 + 68],                        a12 = imgS[i0 + 70];
        int a20 = imgS[i0 + 136], a21 = imgS[i0 + 137], a22 = imgS[i0 + 138];
        int gxv = (a02 + 2 * a12 + a22) - (a00 + 2 * a10 + a20);
        int gyv = (a20 + 2 * a21 + a22) - (a00 + 2 * a01 + a02);
        magS[idx] = (unsigned short)(abs(gxv) + abs(gyv));
    }
    __syncthreads();

    // NMS + thresholds: wave wv handles contiguous 8-row band
    const int lane = tid & 63;
    const int wv = tid >> 6;
    for (int i = 0; i < 8; ++i) {
        int rr = wv * 8 + i;
        int gyp = y0 + rr;
        int ic = (rr + 2) * 68 + lane + 2;  // img center
        int mc = (rr + 1) * 66 + lane + 1;  // mag center
        int a00 = imgS[ic - 69], a01 = imgS[ic - 68], a02 = imgS[ic - 67];
        int a10 = imgS[ic - 1],                       a12 = imgS[ic + 1];
        int a20 = imgS[ic + 67], a21 = imgS[ic + 68], a22 = imgS[ic + 69];
        int gxv = (a02 + 2 * a12 + a22) - (a00 + 2 * a10 + a20);
        int gyv = (a20 + 2 * a21 + a22) - (a00 + 2 * a01 + a02);
        int mag = magS[mc];

        // exact direction class via tan(22.5)=sqrt2-1, tan(67.5)=sqrt2+1 (int squares)
        int ay = gyv, ax = gxv;
        if (ay < 0) { ay = -ay; ax = -ax; }
        int cls;
        if (ay == 0) cls = 0;
        else if (ax > 0) {
            long long s = ay + ax, q = 2LL * ax * ax;
            if (s * s < q) cls = 0;
            else { long long t = ay - ax; cls = (t < 0 || t * t < q) ? 1 : 2; }
        } else if (ax == 0) cls = 2;
        else {
            long long h = -(long long)ax, s = ay + h, q = 2LL * h * h;
            if (s * s < q) cls = 0;
            else { long long t = ay - h; cls = (t > 0 && t * t > q) ? 2 : 3; }
        }
        int n1, n2;
        if (cls == 0)      { n1 = magS[mc + 1];  n2 = magS[mc - 1]; }
        else if (cls == 1) { n1 = magS[mc - 65]; n2 = magS[mc + 65]; }
        else if (cls == 2) { n1 = magS[mc - 66]; n2 = magS[mc + 66]; }
        else               { n1 = magS[mc - 67]; n2 = magS[mc + 67]; }

        bool keep = (mag >= n1) && (mag > n2) && (gyp > 0) && (gyp < HH - 1);
        bool weak = keep && (mag > 100);
        bool strong = keep && (mag > 200);
        u64 ww = __ballot(weak);
        u64 sw = __ballot(strong);
        if (lane == 0) {
            u64 m = ~0ull;
            if (x0 == 0) m &= ~1ull;
            if (x0 + 64 == WW) m &= ~(1ull << 63);
            wRow[rr] = ww & m;
            sRow[rr] = sw & m;
        }
    }
    __syncthreads();   // imgS/magS no longer read; safe to alias fl over imgS

    for (int i = tid; i < 4097; i += 512) fl[i] = i;   // fl[0]=0 virtual strong root
    __syncthreads();

    // local unions: thread -> (row r, 8-bit octant o); nodes are pixel+1
    {
        const int r = tid >> 3, o = tid & 7;
        const u64 omask = 0xFFull << (o * 8);
        const u64 w = wRow[r];
        const u64 above = r ? wRow[r - 1] : 0;
        const int base = r * 64 + 1;           // +1 node bias
        u64 m;
        m = (w & (w >> 1)) & omask;            // horizontal (b, b+1)
        while (m) { int b = __builtin_ctzll(m); m &= m - 1; uniteL(fl, base + b, base + b + 1); }
        m = (w & above) & omask;               // up
        while (m) { int b = __builtin_ctzll(m); m &= m - 1; uniteL(fl, base + b, base - 64 + b); }
        m = (w & (above << 1)) & omask;        // up-left
        while (m) { int b = __builtin_ctzll(m); m &= m - 1; uniteL(fl, base + b, base - 64 + b - 1); }
        m = (w & (above >> 1)) & omask;        // up-right
        while (m) { int b = __builtin_ctzll(m); m &= m - 1; uniteL(fl, base + b, base - 64 + b + 1); }
        m = sRow[r] & omask;                   // strong -> virtual node 0
        while (m) { int b = __builtin_ctzll(m); m &= m - 1; uniteL(fl, 0, base + b); }
    }
    __syncthreads();

    // write-out: full local compression; strong comps -> 0; non-weak -> identity.
    // (tile (0,0) writes f[0] = 0 here: pixel 0 is border -> non-weak -> val=g=0)
    for (int k = 0; k < 8; ++k) {
        int i = k * 512 + tid;
        int rr = i >> 6, cc = i & 63;
        int g = (y0 + rr) * WW + x0 + cc;
        int val = g;
        if ((wRow[rr] >> cc) & 1ull) {
            int rt = findRootL(fl, i + 1);
            val = (rt == 0) ? 0 : (y0 + ((rt - 1) >> 6)) * WW + x0 + ((rt - 1) & 63);
        }
        f[g] = val;
    }
    if (tid < 64) {
        weakG[(y0 + tid) * WPR + blockIdx.x] = wRow[tid];
        strongG[(y0 + tid) * WPR + blockIdx.x] = sRow[tid];
    }
}

// ---------------- Kernel 2: cross-tile boundary unions, 1 thread per boundary px ----
__global__ __launch_bounds__(256) void canny_boundary(
    const u64* __restrict__ weakG, int* __restrict__ f)
{
    int t = blockIdx.x * 256 + threadIdx.x;
    if (t < 65536) {
        // (a) vertical word boundaries: word pair (c, c+1), all rows
        int y = t >> 5, c = t & 31;
        if (c == 31) return;
        u64 w0 = weakG[y * WPR + c];
        u64 w1 = weakG[y * WPR + c + 1];
        int a = (int)(w0 >> 63) & 1, b = (int)w1 & 1;
        if (!(a | b)) return;
        int p63 = y * WW + c * 64 + 63;
        int p64 = p63 + 1;
        if (a & b) unite(f, p63, p64);
        if (y < HH - 1) {
            u64 w0d = weakG[(y + 1) * WPR + c];
            u64 w1d = weakG[(y + 1) * WPR + c + 1];
            if (a && (w1d & 1ull)) unite(f, p63, p64 + WW);
            if (b && (w0d >> 63)) unite(f, p64, p63 + WW);
        }
    } else {
        // (b) horizontal tile boundaries: one thread per pixel on rows y=63,127,...
        int idx = t - 65536;
        if (idx >= 31 * 2048) return;
        int y = 63 + (idx >> 11) * 64;
        int xx = idx & 2047;
        u64 w = weakG[y * WPR + (xx >> 6)];
        if (!((w >> (xx & 63)) & 1ull)) return;
        int p = y * WW + xx;
        u64 wd = weakG[(y + 1) * WPR + (xx >> 6)];
        if ((wd >> (xx & 63)) & 1ull) unite(f, p, p + WW);
        if (xx > 0) {
            u64 wl = weakG[(y + 1) * WPR + ((xx - 1) >> 6)];
            if ((wl >> ((xx - 1) & 63)) & 1ull) unite(f, p, p + WW - 1);
        }
        if (xx < WW - 1) {
            u64 wr = weakG[(y + 1) * WPR + ((xx + 1) >> 6)];
            if ((wr >> ((xx + 1) & 63)) & 1ull) unite(f, p, p + WW + 1);
        }
    }
}

// ---------------- Kernel 3: edge query fused with coalesced 3ch write ----------------
// f[g]==0 -> edge; f[g]==g -> not edge (weak root of strong-free comp, or non-weak);
// else rare short chase. f loads are coalesced int4 vectors.
__global__ __launch_bounds__(256) void canny_edgefuse(
    const u64* __restrict__ weakG, const int* __restrict__ f, float* __restrict__ out)
{
    __shared__ unsigned short eS[256];
    const int tid = threadIdx.x;
    const int B = blockIdx.x * 4096;          // px segment base
    const int px0 = B + tid * 16;
    u64 w = weakG[px0 >> 6];
    u32 bits = (u32)(w >> (px0 & 63)) & 0xFFFFu;
    u32 e = 0;
    if (bits) {
        const int4* fq = reinterpret_cast<const int4*>(f + px0);
        #pragma unroll
        for (int j = 0; j < 4; ++j) {
            int4 q = fq[j];
            #pragma unroll
            for (int k = 0; k < 4; ++k) {
                int b = j * 4 + k;
                if ((bits >> b) & 1u) {
                    int v = (k == 0) ? q.x : (k == 1) ? q.y : (k == 2) ? q.z : q.w;
                    int ed;
                    if (v == 0) ed = 1;
                    else if (v == px0 + b) ed = 0;
                    else ed = (findRootRO(f, v) == 0);
                    e |= (u32)ed << b;
                }
            }
        }
    }
    eS[tid] = (unsigned short)e;
    __syncthreads();

    #pragma unroll
    for (int ch = 0; ch < 3; ++ch) {
        #pragma unroll
        for (int j = 0; j < 4; ++j) {
            int idx = j * 256 + tid;              // float4 index within segment
            u32 eb = (u32)(eS[idx >> 2] >> ((idx & 3) * 4)) & 0xFu;
            float4 v;
            v.x = (float)(eb & 1u);
            v.y = (float)((eb >> 1) & 1u);
            v.z = (float)((eb >> 2) & 1u);
            v.w = (float)((eb >> 3) & 1u);
            *reinterpret_cast<float4*>(out + (size_t)ch * NPIX + B + idx * 4) = v;
        }
    }
}

// ---------------- Fallback path (small ws): prep + proven cooperative hysteresis ----
__global__ __launch_bounds__(256) void canny_prep(
    const float* __restrict__ x, u64* __restrict__ weakG,
    u64* __restrict__ strongG, unsigned int* __restrict__ flags)
{
    __shared__ int imgS[20][68];
    __shared__ int magS[18][68];
    const int tid = threadIdx.x;
    const int tx0 = blockIdx.x * 64;
    const int ty0 = blockIdx.y * 16;

    if (flags && blockIdx.x == 0 && blockIdx.y == 0 && tid < 2) flags[tid] = 0u;

    for (int idx = tid; idx < 20 * 68; idx += 256) {
        int r = idx / 68, c = idx - r * 68;
        int gy = ty0 - 2 + r; gy = gy < 0 ? 0 : (gy > HH - 1 ? HH - 1 : gy);
        int gx = tx0 - 2 + c; gx = gx < 0 ? 0 : (gx > WW - 1 ? WW - 1 : gx);
        float v = floorf(x[gy * WW + gx] * 255.0f);
        v = fminf(fmaxf(v, 0.0f), 255.0f);
        imgS[r][c] = (int)v;
    }
    __syncthreads();

    for (int idx = tid; idx < 18 * 66; idx += 256) {
        int r = idx / 66, c = idx - r * 66;
        int a00 = imgS[r][c],     a01 = imgS[r][c + 1],     a02 = imgS[r][c + 2];
        int a10 = imgS[r + 1][c],                           a12 = imgS[r + 1][c + 2];
        int a20 = imgS[r + 2][c], a21 = imgS[r + 2][c + 1], a22 = imgS[r + 2][c + 2];
        int gxv = (a02 + 2 * a12 + a22) - (a00 + 2 * a10 + a20);
        int gyv = (a20 + 2 * a21 + a22) - (a00 + 2 * a01 + a02);
        magS[r][c] = abs(gxv) + abs(gyv);
    }
    __syncthreads();

    const int lane = tid & 63;
    const int wv = tid >> 6;
    for (int i = 0; i < 4; ++i) {
        int rr = wv * 4 + i;
        int gyp = ty0 + rr;
        int r = rr + 1, c = lane + 1;
        int a00 = imgS[rr + 1][lane + 1], a01 = imgS[rr + 1][lane + 2], a02 = imgS[rr + 1][lane + 3];
        int a10 = imgS[rr + 2][lane + 1],                               a12 = imgS[rr + 2][lane + 3];
        int a20 = imgS[rr + 3][lane + 1], a21 = imgS[rr + 3][lane + 2], a22 = imgS[rr + 3][lane + 3];
        int gxv = (a02 + 2 * a12 + a22) - (a00 + 2 * a10 + a20);
        int gyv = (a20 + 2 * a21 + a22) - (a00 + 2 * a01 + a02);
        int mag = magS[r][c];

        int ay = gyv, ax = gxv;
        if (ay < 0) { ay = -ay; ax = -ax; }
        int cls;
        if (ay == 0) cls = 0;
        else if (ax > 0) {
            long long s = ay + ax, q = 2LL * ax * ax;
            if (s * s < q) cls = 0;
            else { long long t = ay - ax; cls = (t < 0 || t * t < q) ? 1 : 2; }
        } else if (ax == 0) cls = 2;
        else {
            long long h = -(long long)ax, s = ay + h, q = 2LL * h * h;
            if (s * s < q) cls = 0;
            else { long long t = ay - h; cls = (t > 0 && t * t > q) ? 2 : 3; }
        }
        int n1, n2;
        if (cls == 0)      { n1 = magS[r][c + 1];     n2 = magS[r][c - 1]; }
        else if (cls == 1) { n1 = magS[r - 1][c + 1]; n2 = magS[r + 1][c - 1]; }
        else if (cls == 2) { n1 = magS[r - 1][c];     n2 = magS[r + 1][c]; }
        else               { n1 = magS[r - 1][c - 1]; n2 = magS[r + 1][c + 1]; }

        bool keep = (mag >= n1) && (mag > n2) && (gyp > 0) && (gyp < HH - 1);
        bool weak = keep && (mag > 100);
        bool strong = keep && (mag > 200);
        u64 ww = __ballot(weak);
        u64 sw = __ballot(strong);
        if (lane == 0) {
            u64 mm = ~0ull;
            if (tx0 == 0) mm &= ~1ull;
            if (tx0 + 64 == WW) mm &= ~(1ull << 63);
            int widx = gyp * WPR + (tx0 >> 6);
            weakG[widx] = ww & mm;
            strongG[widx] = sw & mm;
        }
    }
}

__global__ __launch_bounds__(256) void canny_hyst(
    const u64* __restrict__ weakG, u64* __restrict__ edgeG,
    unsigned int* __restrict__ flags, float* __restrict__ out)
{
    cg::grid_group grid = cg::this_grid();
    const int tid = threadIdx.x;
    const int b = blockIdx.x;
    const int r = tid >> 5;
    const int c = tid & 31;
    const int row0 = b * 8;
    __shared__ u64 weakL[8][32];
    __shared__ u64 edgeL[10][32];
    __shared__ int sChg[2];
    __shared__ int sAny;

    weakL[r][c] = weakG[(row0 + r) * WPR + c];
    edgeL[r + 1][c] = edgeG[(row0 + r) * WPR + c];

    int iter = 0;
    for (;;) {
        if (tid < 32) {
            u64 v = 0;
            if (b > 0) v = __hip_atomic_load(&edgeG[(row0 - 1) * WPR + tid],
                                             __ATOMIC_RELAXED, __HIP_MEMORY_SCOPE_AGENT);
            edgeL[0][tid] = v;
        } else if (tid < 64) {
            int cc = tid - 32;
            u64 v = 0;
            if (b < (int)gridDim.x - 1)
                v = __hip_atomic_load(&edgeG[(row0 + 8) * WPR + cc],
                                      __ATOMIC_RELAXED, __HIP_MEMORY_SCOPE_AGENT);
            edgeL[9][cc] = v;
        }
        if (tid == 0) sAny = 0;
        if (tid < 2) sChg[tid] = 0;
        __syncthreads();

        int p = 0;
        for (;;) {
            u64 up = edgeL[r][c],     upl = c ? edgeL[r][c - 1] : 0,     upr = (c < 31) ? edgeL[r][c + 1] : 0;
            u64 mi = edgeL[r + 1][c], mil = c ? edgeL[r + 1][c - 1] : 0, mir = (c < 31) ? edgeL[r + 1][c + 1] : 0;
            u64 dn = edgeL[r + 2][c], dnl = c ? edgeL[r + 2][c - 1] : 0, dnr = (c < 31) ? edgeL[r + 2][c + 1] : 0;
            u64 A = up | (up << 1) | (up >> 1) | (upl >> 63) | (upr << 63);
            u64 B = mi | (mi << 1) | (mi >> 1) | (mil >> 63) | (mir << 63);
            u64 C = dn | (dn << 1) | (dn >> 1) | (dnl >> 63) | (dnr << 63);
            u64 ne = mi | (weakL[r][c] & (A | B | C));
            bool chg = (ne != mi);
            __syncthreads();
            edgeL[r + 1][c] = ne;
            if (chg) { sChg[p] = 1; sAny = 1; }
            if (tid == 0) sChg[p ^ 1] = 0;
            __syncthreads();
            if (!sChg[p]) break;
            p ^= 1;
        }

        if (sAny) edgeG[(row0 + r) * WPR + c] = edgeL[r + 1][c];
        if (sAny && tid == 0) atomicOr(&flags[iter & 1], 1u);
        __threadfence();
        grid.sync();
        unsigned fl2 = __hip_atomic_load(&flags[iter & 1], __ATOMIC_ACQUIRE, __HIP_MEMORY_SCOPE_AGENT);
        if (tid == 0) flags[(iter + 1) & 1] = 0u;
        __threadfence();
        grid.sync();
        if (fl2 == 0) break;
        ++iter;
    }

    for (int chn = 0; chn < 3; ++chn) {
        for (int rr = 0; rr < 8; ++rr) {
            size_t base2 = ((size_t)chn * HH + (size_t)(row0 + rr)) * WW;
            for (int k = tid; k < 512; k += 256) {
                u64 w = edgeL[rr + 1][k >> 4];
                int sh = (k & 15) * 4;
                float4 v;
                v.x = (float)((w >> sh) & 1ull);
                v.y = (float)((w >> (sh + 1)) & 1ull);
                v.z = (float)((w >> (sh + 2)) & 1ull);
                v.w = (float)((w >> (sh + 3)) & 1ull);
                *reinterpret_cast<float4*>(out + base2 + (size_t)k * 4) = v;
            }
        }
    }
}

extern "C" void kernel_launch(void* const* d_in, const int* in_sizes, int n_in,
                              void* d_out, int out_size, void* d_ws, size_t ws_size,
                              hipStream_t stream) {
    const float* x = (const float*)d_in[0];
    float* out = (float*)d_out;

    const size_t BM = (size_t)NWORDS * 8;          // 512 KB per bitmap
    const size_t need = 2 * BM + (size_t)NPIX * 4; // weak + strong + labels = 17 MB

    if (ws_size >= need) {
        u64* weakG   = (u64*)d_ws;
        u64* strongG = weakG + NWORDS;
        int* f = (int*)(strongG + NWORDS);

        hipLaunchKernelGGL(canny_tile, dim3(32, 32), dim3(512), 0, stream,
                           x, weakG, strongG, f);
        hipLaunchKernelGGL(canny_boundary, dim3((65536 + 31 * 2048 + 255) / 256), dim3(256),
                           0, stream, weakG, f);
        hipLaunchKernelGGL(canny_edgefuse, dim3(NPIX / 4096), dim3(256), 0, stream,
                           weakG, f, out);
    } else {
        u64* edgeG = (u64*)d_ws;
        u64* weakG = edgeG + NWORDS;
        unsigned int* flags = (unsigned int*)(weakG + NWORDS);
        hipLaunchKernelGGL(canny_prep, dim3(WW / 64, HH / 16), dim3(256), 0, stream,
                           x, weakG, edgeG, flags);
        void* args[] = { (void*)&weakG, (void*)&edgeG, (void*)&flags, (void*)&out };
        hipLaunchCooperativeKernel((void*)canny_hyst, dim3(256), dim3(256), args, 0, stream);
    }
}

// Round 7
// 125.845 us; speedup vs baseline: 3.4456x; 1.0152x over previous
//
#include <hip/hip_runtime.h>
#include <hip/hip_cooperative_groups.h>

namespace cg = cooperative_groups;

#define HH 2048
#define WW 2048
#define WPR 32            // 64-bit words per image row
#define NPIX (HH * WW)
#define NWORDS (HH * WPR)

typedef unsigned long long u64;
typedef unsigned int u32;

// ---------------- global union-find (ECL-CC style, lock-free) ----------------
// Invariant: f[i] <= i (links point to smaller indices) -> acyclic.
__device__ inline int findRoot(int* __restrict__ f, int i) {
    int p = __hip_atomic_load(&f[i], __ATOMIC_RELAXED, __HIP_MEMORY_SCOPE_AGENT);
    while (p != i) {
        int gp = __hip_atomic_load(&f[p], __ATOMIC_RELAXED, __HIP_MEMORY_SCOPE_AGENT);
        if (gp != p)
            __hip_atomic_store(&f[i], gp, __ATOMIC_RELAXED, __HIP_MEMORY_SCOPE_AGENT);
        i = p; p = gp;
    }
    return i;
}

__device__ inline void unite(int* __restrict__ f, int a, int b) {
    int ra = findRoot(f, a), rb = findRoot(f, b);
    while (ra != rb) {
        if (ra > rb) { int t = ra; ra = rb; rb = t; }
        int old = atomicCAS(&f[rb], rb, ra);
        if (old == rb || old == ra) return;
        rb = findRoot(f, old);   // fresh value -> guaranteed progress
    }
}

// read-only root chase (trees are shallow post-compression)
__device__ inline int findRootRO(const int* __restrict__ f, int i) {
    int p = __hip_atomic_load(&f[i], __ATOMIC_RELAXED, __HIP_MEMORY_SCOPE_AGENT);
    while (true) {
        int gp = __hip_atomic_load(&f[p], __ATOMIC_RELAXED, __HIP_MEMORY_SCOPE_AGENT);
        if (gp == p) return p;
        p = gp;
    }
}

// ---------------- LDS-local union-find ----------------
__device__ inline int findRootL(volatile int* fl, int i) {
    int p = fl[i];
    while (p != i) {
        int gp = fl[p];
        if (gp != p) fl[i] = gp;   // halving; benign race
        i = p; p = gp;
    }
    return i;
}

__device__ inline void uniteL(int* fl, int a, int b) {
    int ra = findRootL(fl, a), rb = findRootL(fl, b);
    while (ra != rb) {
        if (ra > rb) { int t = ra; ra = rb; rb = t; }
        int old = atomicCAS(&fl[rb], rb, ra);
        if (old == rb || old == ra) return;
        rb = findRootL(fl, old);
    }
}

// exact direction class via tan(22.5)=sqrt2-1, tan(67.5)=sqrt2+1.
// Pure int32: |gx|,|gy| <= 1020 -> s*s <= 4.17e6, q <= 2.09e6 (exact).
__device__ inline int dirClass(int gxv, int gyv) {
    int ay = gyv, ax = gxv;
    if (ay < 0) { ay = -ay; ax = -ax; }
    if (ay == 0) return 0;
    if (ax > 0) {
        int s = ay + ax, q = 2 * ax * ax;
        if (s * s < q) return 0;
        int t = ay - ax;
        return (t < 0 || t * t < q) ? 1 : 2;
    }
    if (ax == 0) return 2;
    int h = -ax, s = ay + h, q = 2 * h * h;
    if (s * s < q) return 0;
    int t = ay - h;
    return (t > 0 && t * t > q) ? 2 : 3;
}

// ---------------- Kernel 1 (fused): quantize+Sobel+NMS+thresholds+LOCAL CC ----------
// 64x64 tile per block, 512 threads. Local node 0 is a VIRTUAL strong super-root
// (pixels are 1..4096). Strong-containing components end at root 0 -> f = 0
// (global pixel 0 is border -> never weak -> global index 0 free as super-root).
__global__ __launch_bounds__(512) void canny_tile(
    const float* __restrict__ x, u64* __restrict__ weakG,
    u64* __restrict__ strongG, int* __restrict__ f)
{
    __shared__ int imgS[68 * 68];            // quantized img, halo 2; REUSED as fl[4097]
    __shared__ unsigned short magS[66 * 66]; // (cls<<12) | mag  (mag<=2040<4096)
    __shared__ u64 wRow[64], sRow[64];
    int* fl = imgS;                          // alias (4624 >= 4097), phases disjoint

    const int tid = threadIdx.x;
    const int x0 = blockIdx.x * 64;
    const int y0 = blockIdx.y * 64;

    // stage 68x68 quantized image (exact fp32 floor(x*255) clip), replicate border
    for (int idx = tid; idx < 68 * 68; idx += 512) {
        int r = idx / 68, c = idx - r * 68;
        int gy = y0 - 2 + r; gy = gy < 0 ? 0 : (gy > HH - 1 ? HH - 1 : gy);
        int gx = x0 - 2 + c; gx = gx < 0 ? 0 : (gx > WW - 1 ? WW - 1 : gx);
        float v = floorf(x[gy * WW + gx] * 255.0f);
        v = fminf(fmaxf(v, 0.0f), 255.0f);
        imgS[idx] = (int)v;
    }
    __syncthreads();

    // Sobel ONCE per 66x66 item: pack (cls<<12)|mag  (integer exact)
    for (int idx = tid; idx < 66 * 66; idx += 512) {
        int r = idx / 66, c = idx - r * 66;
        int i0 = r * 68 + c;
        int a00 = imgS[i0],       a01 = imgS[i0 + 1],   a02 = imgS[i0 + 2];
        int a10 = imgS[i0 + 68],                        a12 = imgS[i0 + 70];
        int a20 = imgS[i0 + 136], a21 = imgS[i0 + 137], a22 = imgS[i0 + 138];
        int gxv = (a02 + 2 * a12 + a22) - (a00 + 2 * a10 + a20);
        int gyv = (a20 + 2 * a21 + a22) - (a00 + 2 * a01 + a02);
        int mag = abs(gxv) + abs(gyv);
        int cls = dirClass(gxv, gyv);
        magS[idx] = (unsigned short)((cls << 12) | mag);
    }
    __syncthreads();   // imgS dead from here (NMS uses only magS) -> fl aliases imgS

    // NMS + thresholds (reads magS only) and fl init, same phase
    const int lane = tid & 63;
    const int wv = tid >> 6;
    for (int i = 0; i < 8; ++i) {
        int rr = wv * 8 + i;
        int gyp = y0 + rr;
        int mc = (rr + 1) * 66 + lane + 1;
        int mv = magS[mc];
        int cls = mv >> 12;
        int mag = mv & 0xFFF;
        // cls0: L/R (+1/-1); cls1: -65/+65; cls2: -66/+66; cls3: -67/+67
        int d1 = (cls == 0) ? -1 : 64 + cls;
        int n1 = magS[mc - d1] & 0xFFF;
        int n2 = magS[mc + d1] & 0xFFF;
        bool keep = (mag >= n1) && (mag > n2) && (gyp > 0) && (gyp < HH - 1);
        bool weak = keep && (mag > 100);
        bool strong = keep && (mag > 200);
        u64 ww = __ballot(weak);
        u64 sw = __ballot(strong);
        if (lane == 0) {
            u64 m = ~0ull;
            if (x0 == 0) m &= ~1ull;
            if (x0 + 64 == WW) m &= ~(1ull << 63);
            wRow[rr] = ww & m;
            sRow[rr] = sw & m;
        }
    }
    for (int i = tid; i < 4097; i += 512) fl[i] = i;   // fl[0]=0 virtual strong root
    __syncthreads();

    // local unions: thread -> (row r, 8-bit octant o); nodes are pixel+1
    {
        const int r = tid >> 3, o = tid & 7;
        const u64 omask = 0xFFull << (o * 8);
        const u64 w = wRow[r];
        const u64 above = r ? wRow[r - 1] : 0;
        const int base = r * 64 + 1;           // +1 node bias
        u64 m;
        m = (w & (w >> 1)) & omask;            // horizontal (b, b+1)
        while (m) { int b = __builtin_ctzll(m); m &= m - 1; uniteL(fl, base + b, base + b + 1); }
        m = (w & above) & omask;               // up
        while (m) { int b = __builtin_ctzll(m); m &= m - 1; uniteL(fl, base + b, base - 64 + b); }
        m = (w & (above << 1)) & omask;        // up-left
        while (m) { int b = __builtin_ctzll(m); m &= m - 1; uniteL(fl, base + b, base - 64 + b - 1); }
        m = (w & (above >> 1)) & omask;        // up-right
        while (m) { int b = __builtin_ctzll(m); m &= m - 1; uniteL(fl, base + b, base - 64 + b + 1); }
        m = sRow[r] & omask;                   // strong -> virtual node 0
        while (m) { int b = __builtin_ctzll(m); m &= m - 1; uniteL(fl, 0, base + b); }
    }
    __syncthreads();

    // write-out: full local compression; strong comps -> 0; non-weak -> identity.
    // (tile (0,0) writes f[0] = 0 here: pixel 0 is border -> non-weak -> val=g=0)
    for (int k = 0; k < 8; ++k) {
        int i = k * 512 + tid;
        int rr = i >> 6, cc = i & 63;
        int g = (y0 + rr) * WW + x0 + cc;
        int val = g;
        if ((wRow[rr] >> cc) & 1ull) {
            int rt = findRootL(fl, i + 1);
            val = (rt == 0) ? 0 : (y0 + ((rt - 1) >> 6)) * WW + x0 + ((rt - 1) & 63);
        }
        f[g] = val;
    }
    if (tid < 64) {
        weakG[(y0 + tid) * WPR + blockIdx.x] = wRow[tid];
        strongG[(y0 + tid) * WPR + blockIdx.x] = sRow[tid];
    }
}

// ---------------- Kernel 2: cross-tile boundary unions, 1 thread per boundary px ----
__global__ __launch_bounds__(256) void canny_boundary(
    const u64* __restrict__ weakG, int* __restrict__ f)
{
    int t = blockIdx.x * 256 + threadIdx.x;
    if (t < 65536) {
        // (a) vertical word boundaries: word pair (c, c+1), all rows
        int y = t >> 5, c = t & 31;
        if (c == 31) return;
        u64 w0 = weakG[y * WPR + c];
        u64 w1 = weakG[y * WPR + c + 1];
        int a = (int)(w0 >> 63) & 1, b = (int)w1 & 1;
        if (!(a | b)) return;
        int p63 = y * WW + c * 64 + 63;
        int p64 = p63 + 1;
        if (a & b) unite(f, p63, p64);
        if (y < HH - 1) {
            u64 w0d = weakG[(y + 1) * WPR + c];
            u64 w1d = weakG[(y + 1) * WPR + c + 1];
            if (a && (w1d & 1ull)) unite(f, p63, p64 + WW);
            if (b && (w0d >> 63)) unite(f, p64, p63 + WW);
        }
    } else {
        // (b) horizontal tile boundaries: one thread per pixel on rows y=63,127,...
        int idx = t - 65536;
        if (idx >= 31 * 2048) return;
        int y = 63 + (idx >> 11) * 64;
        int xx = idx & 2047;
        u64 w = weakG[y * WPR + (xx >> 6)];
        if (!((w >> (xx & 63)) & 1ull)) return;
        int p = y * WW + xx;
        u64 wd = weakG[(y + 1) * WPR + (xx >> 6)];
        if ((wd >> (xx & 63)) & 1ull) unite(f, p, p + WW);
        if (xx > 0) {
            u64 wl = weakG[(y + 1) * WPR + ((xx - 1) >> 6)];
            if ((wl >> ((xx - 1) & 63)) & 1ull) unite(f, p, p + WW - 1);
        }
        if (xx < WW - 1) {
            u64 wr = weakG[(y + 1) * WPR + ((xx + 1) >> 6)];
            if ((wr >> ((xx + 1) & 63)) & 1ull) unite(f, p, p + WW + 1);
        }
    }
}

// ---------------- Kernel 3: edge query fused with coalesced 3ch write ----------------
// f[g]==0 -> edge; f[g]==g -> not edge; else rare short chase (memoized).
__global__ __launch_bounds__(256) void canny_edgefuse(
    const u64* __restrict__ weakG, const int* __restrict__ f, float* __restrict__ out)
{
    __shared__ unsigned short eS[256];
    const int tid = threadIdx.x;
    const int B = blockIdx.x * 4096;          // px segment base
    const int px0 = B + tid * 16;
    u64 w = weakG[px0 >> 6];
    u32 bits = (u32)(w >> (px0 & 63)) & 0xFFFFu;
    u32 e = 0;
    if (bits) {
        const int4* fq = reinterpret_cast<const int4*>(f + px0);
        int lastp = -1, laste = 0;
        #pragma unroll
        for (int j = 0; j < 4; ++j) {
            int4 q = fq[j];
            #pragma unroll
            for (int k = 0; k < 4; ++k) {
                int b = j * 4 + k;
                if ((bits >> b) & 1u) {
                    int v = (k == 0) ? q.x : (k == 1) ? q.y : (k == 2) ? q.z : q.w;
                    int ed;
                    if (v == 0) ed = 1;
                    else if (v == px0 + b) ed = 0;
                    else if (v == lastp) ed = laste;
                    else { ed = (findRootRO(f, v) == 0); lastp = v; laste = ed; }
                    e |= (u32)ed << b;
                }
            }
        }
    }
    eS[tid] = (unsigned short)e;
    __syncthreads();

    #pragma unroll
    for (int ch = 0; ch < 3; ++ch) {
        #pragma unroll
        for (int j = 0; j < 4; ++j) {
            int idx = j * 256 + tid;              // float4 index within segment
            u32 eb = (u32)(eS[idx >> 2] >> ((idx & 3) * 4)) & 0xFu;
            float4 v;
            v.x = (float)(eb & 1u);
            v.y = (float)((eb >> 1) & 1u);
            v.z = (float)((eb >> 2) & 1u);
            v.w = (float)((eb >> 3) & 1u);
            *reinterpret_cast<float4*>(out + (size_t)ch * NPIX + B + idx * 4) = v;
        }
    }
}

// ---------------- Fallback path (small ws): prep + proven cooperative hysteresis ----
__global__ __launch_bounds__(256) void canny_prep(
    const float* __restrict__ x, u64* __restrict__ weakG,
    u64* __restrict__ strongG, unsigned int* __restrict__ flags)
{
    __shared__ int imgS[20][68];
    __shared__ int magS[18][68];
    const int tid = threadIdx.x;
    const int tx0 = blockIdx.x * 64;
    const int ty0 = blockIdx.y * 16;

    if (flags && blockIdx.x == 0 && blockIdx.y == 0 && tid < 2) flags[tid] = 0u;

    for (int idx = tid; idx < 20 * 68; idx += 256) {
        int r = idx / 68, c = idx - r * 68;
        int gy = ty0 - 2 + r; gy = gy < 0 ? 0 : (gy > HH - 1 ? HH - 1 : gy);
        int gx = tx0 - 2 + c; gx = gx < 0 ? 0 : (gx > WW - 1 ? WW - 1 : gx);
        float v = floorf(x[gy * WW + gx] * 255.0f);
        v = fminf(fmaxf(v, 0.0f), 255.0f);
        imgS[r][c] = (int)v;
    }
    __syncthreads();

    for (int idx = tid; idx < 18 * 66; idx += 256) {
        int r = idx / 66, c = idx - r * 66;
        int a00 = imgS[r][c],     a01 = imgS[r][c + 1],     a02 = imgS[r][c + 2];
        int a10 = imgS[r + 1][c],                           a12 = imgS[r + 1][c + 2];
        int a20 = imgS[r + 2][c], a21 = imgS[r + 2][c + 1], a22 = imgS[r + 2][c + 2];
        int gxv = (a02 + 2 * a12 + a22) - (a00 + 2 * a10 + a20);
        int gyv = (a20 + 2 * a21 + a22) - (a00 + 2 * a01 + a02);
        magS[r][c] = abs(gxv) + abs(gyv);
    }
    __syncthreads();

    const int lane = tid & 63;
    const int wv = tid >> 6;
    for (int i = 0; i < 4; ++i) {
        int rr = wv * 4 + i;
        int gyp = ty0 + rr;
        int r = rr + 1, c = lane + 1;
        int a00 = imgS[rr + 1][lane + 1], a01 = imgS[rr + 1][lane + 2], a02 = imgS[rr + 1][lane + 3];
        int a10 = imgS[rr + 2][lane + 1],                               a12 = imgS[rr + 2][lane + 3];
        int a20 = imgS[rr + 3][lane + 1], a21 = imgS[rr + 3][lane + 2], a22 = imgS[rr + 3][lane + 3];
        int gxv = (a02 + 2 * a12 + a22) - (a00 + 2 * a10 + a20);
        int gyv = (a20 + 2 * a21 + a22) - (a00 + 2 * a01 + a02);
        int mag = magS[r][c];
        int cls = dirClass(gxv, gyv);
        int n1, n2;
        if (cls == 0)      { n1 = magS[r][c + 1];     n2 = magS[r][c - 1]; }
        else if (cls == 1) { n1 = magS[r - 1][c + 1]; n2 = magS[r + 1][c - 1]; }
        else if (cls == 2) { n1 = magS[r - 1][c];     n2 = magS[r + 1][c]; }
        else               { n1 = magS[r - 1][c - 1]; n2 = magS[r + 1][c + 1]; }

        bool keep = (mag >= n1) && (mag > n2) && (gyp > 0) && (gyp < HH - 1);
        bool weak = keep && (mag > 100);
        bool strong = keep && (mag > 200);
        u64 ww = __ballot(weak);
        u64 sw = __ballot(strong);
        if (lane == 0) {
            u64 mm = ~0ull;
            if (tx0 == 0) mm &= ~1ull;
            if (tx0 + 64 == WW) mm &= ~(1ull << 63);
            int widx = gyp * WPR + (tx0 >> 6);
            weakG[widx] = ww & mm;
            strongG[widx] = sw & mm;
        }
    }
}

__global__ __launch_bounds__(256) void canny_hyst(
    const u64* __restrict__ weakG, u64* __restrict__ edgeG,
    unsigned int* __restrict__ flags, float* __restrict__ out)
{
    cg::grid_group grid = cg::this_grid();
    const int tid = threadIdx.x;
    const int b = blockIdx.x;
    const int r = tid >> 5;
    const int c = tid & 31;
    const int row0 = b * 8;
    __shared__ u64 weakL[8][32];
    __shared__ u64 edgeL[10][32];
    __shared__ int sChg[2];
    __shared__ int sAny;

    weakL[r][c] = weakG[(row0 + r) * WPR + c];
    edgeL[r + 1][c] = edgeG[(row0 + r) * WPR + c];

    int iter = 0;
    for (;;) {
        if (tid < 32) {
            u64 v = 0;
            if (b > 0) v = __hip_atomic_load(&edgeG[(row0 - 1) * WPR + tid],
                                             __ATOMIC_RELAXED, __HIP_MEMORY_SCOPE_AGENT);
            edgeL[0][tid] = v;
        } else if (tid < 64) {
            int cc = tid - 32;
            u64 v = 0;
            if (b < (int)gridDim.x - 1)
                v = __hip_atomic_load(&edgeG[(row0 + 8) * WPR + cc],
                                      __ATOMIC_RELAXED, __HIP_MEMORY_SCOPE_AGENT);
            edgeL[9][cc] = v;
        }
        if (tid == 0) sAny = 0;
        if (tid < 2) sChg[tid] = 0;
        __syncthreads();

        int p = 0;
        for (;;) {
            u64 up = edgeL[r][c],     upl = c ? edgeL[r][c - 1] : 0,     upr = (c < 31) ? edgeL[r][c + 1] : 0;
            u64 mi = edgeL[r + 1][c], mil = c ? edgeL[r + 1][c - 1] : 0, mir = (c < 31) ? edgeL[r + 1][c + 1] : 0;
            u64 dn = edgeL[r + 2][c], dnl = c ? edgeL[r + 2][c - 1] : 0, dnr = (c < 31) ? edgeL[r + 2][c + 1] : 0;
            u64 A = up | (up << 1) | (up >> 1) | (upl >> 63) | (upr << 63);
            u64 B = mi | (mi << 1) | (mi >> 1) | (mil >> 63) | (mir << 63);
            u64 C = dn | (dn << 1) | (dn >> 1) | (dnl >> 63) | (dnr << 63);
            u64 ne = mi | (weakL[r][c] & (A | B | C));
            bool chg = (ne != mi);
            __syncthreads();
            edgeL[r + 1][c] = ne;
            if (chg) { sChg[p] = 1; sAny = 1; }
            if (tid == 0) sChg[p ^ 1] = 0;
            __syncthreads();
            if (!sChg[p]) break;
            p ^= 1;
        }

        if (sAny) edgeG[(row0 + r) * WPR + c] = edgeL[r + 1][c];
        if (sAny && tid == 0) atomicOr(&flags[iter & 1], 1u);
        __threadfence();
        grid.sync();
        unsigned fl2 = __hip_atomic_load(&flags[iter & 1], __ATOMIC_ACQUIRE, __HIP_MEMORY_SCOPE_AGENT);
        if (tid == 0) flags[(iter + 1) & 1] = 0u;
        __threadfence();
        grid.sync();
        if (fl2 == 0) break;
        ++iter;
    }

    for (int chn = 0; chn < 3; ++chn) {
        for (int rr = 0; rr < 8; ++rr) {
            size_t base2 = ((size_t)chn * HH + (size_t)(row0 + rr)) * WW;
            for (int k = tid; k < 512; k += 256) {
                u64 w = edgeL[rr + 1][k >> 4];
                int sh = (k & 15) * 4;
                float4 v;
                v.x = (float)((w >> sh) & 1ull);
                v.y = (float)((w >> (sh + 1)) & 1ull);
                v.z = (float)((w >> (sh + 2)) & 1ull);
                v.w = (float)((w >> (sh + 3)) & 1ull);
                *reinterpret_cast<float4*>(out + base2 + (size_t)k * 4) = v;
            }
        }
    }
}

extern "C" void kernel_launch(void* const* d_in, const int* in_sizes, int n_in,
                              void* d_out, int out_size, void* d_ws, size_t ws_size,
                              hipStream_t stream) {
    const float* x = (const float*)d_in[0];
    float* out = (float*)d_out;

    const size_t BM = (size_t)NWORDS * 8;          // 512 KB per bitmap
    const size_t need = 2 * BM + (size_t)NPIX * 4; // weak + strong + labels = 17 MB

    if (ws_size >= need) {
        u64* weakG   = (u64*)d_ws;
        u64* strongG = weakG + NWORDS;
        int* f = (int*)(strongG + NWORDS);

        hipLaunchKernelGGL(canny_tile, dim3(32, 32), dim3(512), 0, stream,
                           x, weakG, strongG, f);
        hipLaunchKernelGGL(canny_boundary, dim3((65536 + 31 * 2048 + 255) / 256), dim3(256),
                           0, stream, weakG, f);
        hipLaunchKernelGGL(canny_edgefuse, dim3(NPIX / 4096), dim3(256), 0, stream,
                           weakG, f, out);
    } else {
        u64* edgeG = (u64*)d_ws;
        u64* weakG = edgeG + NWORDS;
        unsigned int* flags = (unsigned int*)(weakG + NWORDS);
        hipLaunchKernelGGL(canny_prep, dim3(WW / 64, HH / 16), dim3(256), 0, stream,
                           x, weakG, edgeG, flags);
        void* args[] = { (void*)&weakG, (void*)&edgeG, (void*)&flags, (void*)&out };
        hipLaunchCooperativeKernel((void*)canny_hyst, dim3(256), dim3(256), args, 0, stream);
    }
}

// Round 8
// 123.815 us; speedup vs baseline: 3.5021x; 1.0164x over previous
//
#include <hip/hip_runtime.h>
#include <hip/hip_cooperative_groups.h>

namespace cg = cooperative_groups;

#define HH 2048
#define WW 2048
#define WPR 32            // 64-bit words per image row
#define NPIX (HH * WW)
#define NWORDS (HH * WPR)

typedef unsigned long long u64;
typedef unsigned int u32;

// ---------------- global union-find (ECL-CC style, lock-free) ----------------
// Invariant: f[i] <= i (links point to smaller indices) -> acyclic.
__device__ inline int findRoot(int* __restrict__ f, int i) {
    int p = __hip_atomic_load(&f[i], __ATOMIC_RELAXED, __HIP_MEMORY_SCOPE_AGENT);
    while (p != i) {
        int gp = __hip_atomic_load(&f[p], __ATOMIC_RELAXED, __HIP_MEMORY_SCOPE_AGENT);
        if (gp != p)
            __hip_atomic_store(&f[i], gp, __ATOMIC_RELAXED, __HIP_MEMORY_SCOPE_AGENT);
        i = p; p = gp;
    }
    return i;
}

__device__ inline void unite(int* __restrict__ f, int a, int b) {
    int ra = findRoot(f, a), rb = findRoot(f, b);
    while (ra != rb) {
        if (ra > rb) { int t = ra; ra = rb; rb = t; }
        int old = atomicCAS(&f[rb], rb, ra);
        if (old == rb || old == ra) return;
        rb = findRoot(f, old);   // fresh value -> guaranteed progress
    }
}

// read-only root chase (trees are shallow post-compression)
__device__ inline int findRootRO(const int* __restrict__ f, int i) {
    int p = __hip_atomic_load(&f[i], __ATOMIC_RELAXED, __HIP_MEMORY_SCOPE_AGENT);
    while (true) {
        int gp = __hip_atomic_load(&f[p], __ATOMIC_RELAXED, __HIP_MEMORY_SCOPE_AGENT);
        if (gp == p) return p;
        p = gp;
    }
}

// ---------------- LDS-local union-find ----------------
__device__ inline int findRootL(volatile int* fl, int i) {
    int p = fl[i];
    while (p != i) {
        int gp = fl[p];
        if (gp != p) fl[i] = gp;   // halving; benign race
        i = p; p = gp;
    }
    return i;
}

__device__ inline void uniteL(int* fl, int a, int b) {
    int ra = findRootL(fl, a), rb = findRootL(fl, b);
    while (ra != rb) {
        if (ra > rb) { int t = ra; ra = rb; rb = t; }
        int old = atomicCAS(&fl[rb], rb, ra);
        if (old == rb || old == ra) return;
        rb = findRootL(fl, old);
    }
}

// exact direction class via tan(22.5)=sqrt2-1, tan(67.5)=sqrt2+1.
// Pure int32: |gx|,|gy| <= 1020 -> s*s <= 4.17e6 (exact).
__device__ inline int dirClass(int gxv, int gyv) {
    int ay = gyv, ax = gxv;
    if (ay < 0) { ay = -ay; ax = -ax; }
    if (ay == 0) return 0;
    if (ax > 0) {
        int s = ay + ax, q = 2 * ax * ax;
        if (s * s < q) return 0;
        int t = ay - ax;
        return (t < 0 || t * t < q) ? 1 : 2;
    }
    if (ax == 0) return 2;
    int h = -ax, s = ay + h, q = 2 * h * h;
    if (s * s < q) return 0;
    int t = ay - h;
    return (t > 0 && t * t > q) ? 2 : 3;
}

// ---------------- Kernel 1 (fused): quantize+Sobel+NMS+thresholds+LOCAL CC ----------
// 64x64 tile per block, 512 threads. Local node 0 is a VIRTUAL strong super-root.
// Emits: edgeBits (final for tile-interior comps), pendBits (weak px of
// border-touching strong-free comps — the only ones cross-tile merges can flip),
// full f labels (compressed), weakG (for the boundary kernel).
__global__ __launch_bounds__(512) void canny_tile(
    const float* __restrict__ x, u64* __restrict__ weakG,
    u64* __restrict__ edgeBits, u64* __restrict__ pendBits, int* __restrict__ f)
{
    __shared__ int imgS[68 * 68];            // quantized img, halo 2; REUSED as fl[4097]
    __shared__ unsigned short magS[66 * 66]; // (cls<<12) | mag  (mag<=2040<4096)
    __shared__ u64 wRow[64], sRow[64];
    __shared__ unsigned char touched[4097];  // local root touches tile border?
    int* fl = imgS;                          // alias (4624 >= 4097), phases disjoint

    const int tid = threadIdx.x;
    const int x0 = blockIdx.x * 64;
    const int y0 = blockIdx.y * 64;

    // stage 68x68 quantized image (exact fp32 floor(x*255) clip), replicate border
    for (int idx = tid; idx < 68 * 68; idx += 512) {
        int r = idx / 68, c = idx - r * 68;
        int gy = y0 - 2 + r; gy = gy < 0 ? 0 : (gy > HH - 1 ? HH - 1 : gy);
        int gx = x0 - 2 + c; gx = gx < 0 ? 0 : (gx > WW - 1 ? WW - 1 : gx);
        float v = floorf(x[gy * WW + gx] * 255.0f);
        v = fminf(fmaxf(v, 0.0f), 255.0f);
        imgS[idx] = (int)v;
    }
    __syncthreads();

    // Sobel ONCE per 66x66 item: pack (cls<<12)|mag  (integer exact)
    for (int idx = tid; idx < 66 * 66; idx += 512) {
        int r = idx / 66, c = idx - r * 66;
        int i0 = r * 68 + c;
        int a00 = imgS[i0],       a01 = imgS[i0 + 1],   a02 = imgS[i0 + 2];
        int a10 = imgS[i0 + 68],                        a12 = imgS[i0 + 70];
        int a20 = imgS[i0 + 136], a21 = imgS[i0 + 137], a22 = imgS[i0 + 138];
        int gxv = (a02 + 2 * a12 + a22) - (a00 + 2 * a10 + a20);
        int gyv = (a20 + 2 * a21 + a22) - (a00 + 2 * a01 + a02);
        int mag = abs(gxv) + abs(gyv);
        int cls = dirClass(gxv, gyv);
        magS[idx] = (unsigned short)((cls << 12) | mag);
    }
    __syncthreads();   // imgS dead from here (NMS reads only magS) -> fl aliases imgS

    // NMS + thresholds (reads magS only); fl/touched init in same phase
    const int lane = tid & 63;
    const int wv = tid >> 6;
    for (int i = 0; i < 8; ++i) {
        int rr = wv * 8 + i;
        int gyp = y0 + rr;
        int mc = (rr + 1) * 66 + lane + 1;
        int mv = magS[mc];
        int cls = mv >> 12;
        int mag = mv & 0xFFF;
        int d1 = (cls == 0) ? -1 : 64 + cls;   // cls0:+1/-1, cls1:-65/+65, cls2:-66/+66, cls3:-67/+67
        int n1 = magS[mc - d1] & 0xFFF;
        int n2 = magS[mc + d1] & 0xFFF;
        bool keep = (mag >= n1) && (mag > n2) && (gyp > 0) && (gyp < HH - 1);
        bool weak = keep && (mag > 100);
        bool strong = keep && (mag > 200);
        u64 ww = __ballot(weak);
        u64 sw = __ballot(strong);
        if (lane == 0) {
            u64 m = ~0ull;
            if (x0 == 0) m &= ~1ull;
            if (x0 + 64 == WW) m &= ~(1ull << 63);
            wRow[rr] = ww & m;
            sRow[rr] = sw & m;
        }
    }
    for (int i = tid; i < 4097; i += 512) { fl[i] = i; touched[i] = 0; }
    __syncthreads();

    // local unions: thread -> (row r, 8-bit octant o); nodes are pixel+1
    {
        const int r = tid >> 3, o = tid & 7;
        const u64 omask = 0xFFull << (o * 8);
        const u64 w = wRow[r];
        const u64 above = r ? wRow[r - 1] : 0;
        const int base = r * 64 + 1;           // +1 node bias
        u64 m;
        m = (w & (w >> 1)) & omask;            // horizontal (b, b+1)
        while (m) { int b = __builtin_ctzll(m); m &= m - 1; uniteL(fl, base + b, base + b + 1); }
        m = (w & above) & omask;               // up
        while (m) { int b = __builtin_ctzll(m); m &= m - 1; uniteL(fl, base + b, base - 64 + b); }
        m = (w & (above << 1)) & omask;        // up-left
        while (m) { int b = __builtin_ctzll(m); m &= m - 1; uniteL(fl, base + b, base - 64 + b - 1); }
        m = (w & (above >> 1)) & omask;        // up-right
        while (m) { int b = __builtin_ctzll(m); m &= m - 1; uniteL(fl, base + b, base - 64 + b + 1); }
        m = sRow[r] & omask;                   // strong -> virtual node 0
        while (m) { int b = __builtin_ctzll(m); m &= m - 1; uniteL(fl, 0, base + b); }
    }
    __syncthreads();

    // mark border-touching components (rows 0/63, cols 0/63 weak pixels)
    if (tid < 256) {
        int grp = tid >> 6;                    // 0: row0, 1: row63, 2: col0, 3: col63
        int ln = tid & 63;
        int node = -1;
        if (grp == 0)      { if ((wRow[0]  >> ln) & 1ull) node = ln + 1; }
        else if (grp == 1) { if ((wRow[63] >> ln) & 1ull) node = 63 * 64 + ln + 1; }
        else if (grp == 2) { if (wRow[ln] & 1ull)         node = ln * 64 + 1; }
        else               { if (wRow[ln] >> 63)          node = ln * 64 + 63 + 1; }
        if (node > 0) touched[findRootL(fl, node)] = 1;
    }
    __syncthreads();

    // write-out: edge = (root==0); pend = weak & !edge & touched[root];
    // f: full compression (strong comps -> 0; non-weak -> identity).
    for (int k = 0; k < 8; ++k) {
        int i = k * 512 + tid;
        int rr = i >> 6, cc = i & 63;
        int g = (y0 + rr) * WW + x0 + cc;
        int val = g;
        bool edge = false, pend = false;
        if ((wRow[rr] >> cc) & 1ull) {
            int rt = findRootL(fl, i + 1);
            if (rt == 0) { edge = true; val = 0; }
            else {
                val = (y0 + ((rt - 1) >> 6)) * WW + x0 + ((rt - 1) & 63);
                pend = touched[rt] != 0;
            }
        }
        f[g] = val;
        u64 eb = __ballot(edge);
        u64 pb = __ballot(pend);
        if (lane == 0) {
            int widx = (y0 + rr) * WPR + (x0 >> 6);
            edgeBits[widx] = eb;
            pendBits[widx] = pb;
        }
    }
    if (tid < 64) weakG[(y0 + tid) * WPR + blockIdx.x] = wRow[tid];
}

// ---------------- Kernel 2: cross-tile boundary unions, 1 thread per boundary px ----
__global__ __launch_bounds__(256) void canny_boundary(
    const u64* __restrict__ weakG, int* __restrict__ f)
{
    int t = blockIdx.x * 256 + threadIdx.x;
    if (t < 65536) {
        // (a) vertical word boundaries: word pair (c, c+1), all rows
        int y = t >> 5, c = t & 31;
        if (c == 31) return;
        u64 w0 = weakG[y * WPR + c];
        u64 w1 = weakG[y * WPR + c + 1];
        int a = (int)(w0 >> 63) & 1, b = (int)w1 & 1;
        if (!(a | b)) return;
        int p63 = y * WW + c * 64 + 63;
        int p64 = p63 + 1;
        if (a & b) unite(f, p63, p64);
        if (y < HH - 1) {
            u64 w0d = weakG[(y + 1) * WPR + c];
            u64 w1d = weakG[(y + 1) * WPR + c + 1];
            if (a && (w1d & 1ull)) unite(f, p63, p64 + WW);
            if (b && (w0d >> 63)) unite(f, p64, p63 + WW);
        }
    } else {
        // (b) horizontal tile boundaries: one thread per pixel on rows y=63,127,...
        int idx = t - 65536;
        if (idx >= 31 * 2048) return;
        int y = 63 + (idx >> 11) * 64;
        int xx = idx & 2047;
        u64 w = weakG[y * WPR + (xx >> 6)];
        if (!((w >> (xx & 63)) & 1ull)) return;
        int p = y * WW + xx;
        u64 wd = weakG[(y + 1) * WPR + (xx >> 6)];
        if ((wd >> (xx & 63)) & 1ull) unite(f, p, p + WW);
        if (xx > 0) {
            u64 wl = weakG[(y + 1) * WPR + ((xx - 1) >> 6)];
            if ((wl >> ((xx - 1) & 63)) & 1ull) unite(f, p, p + WW - 1);
        }
        if (xx < WW - 1) {
            u64 wr = weakG[(y + 1) * WPR + ((xx + 1) >> 6)];
            if ((wr >> ((xx + 1) & 63)) & 1ull) unite(f, p, p + WW + 1);
        }
    }
}

// ---------------- Kernel 3: finalize pend pixels + coalesced 3ch fp32 write --------
// Reads only edge/pend bitmaps (1 MB); chases f only for pend pixels.
__global__ __launch_bounds__(256) void canny_edgefuse(
    const u64* __restrict__ edgeBits, const u64* __restrict__ pendBits,
    const int* __restrict__ f, float* __restrict__ out)
{
    __shared__ unsigned short eS[256];
    const int tid = threadIdx.x;
    const int B = blockIdx.x * 4096;          // px segment base
    const int px0 = B + tid * 16;
    u64 ew = edgeBits[px0 >> 6];
    u64 pw = pendBits[px0 >> 6];
    const int sh = px0 & 63;
    u32 be = (u32)(ew >> sh) & 0xFFFFu;
    u32 bp = (u32)(pw >> sh) & 0xFFFFu;
    if (bp) {
        int lastp = -1, laste = 0;
        do {
            int b = __builtin_ctz(bp); bp &= bp - 1;
            int v = __hip_atomic_load(&f[px0 + b], __ATOMIC_RELAXED, __HIP_MEMORY_SCOPE_AGENT);
            int ed;
            if (v == 0) ed = 1;
            else if (v == px0 + b) ed = 0;
            else if (v == lastp) ed = laste;
            else { ed = (findRootRO(f, v) == 0); lastp = v; laste = ed; }
            be |= (u32)ed << b;
        } while (bp);
    }
    eS[tid] = (unsigned short)be;
    __syncthreads();

    #pragma unroll
    for (int ch = 0; ch < 3; ++ch) {
        #pragma unroll
        for (int j = 0; j < 4; ++j) {
            int idx = j * 256 + tid;              // float4 index within segment
            u32 eb = (u32)(eS[idx >> 2] >> ((idx & 3) * 4)) & 0xFu;
            float4 v;
            v.x = (float)(eb & 1u);
            v.y = (float)((eb >> 1) & 1u);
            v.z = (float)((eb >> 2) & 1u);
            v.w = (float)((eb >> 3) & 1u);
            *reinterpret_cast<float4*>(out + (size_t)ch * NPIX + B + idx * 4) = v;
        }
    }
}

// ---------------- Fallback path (small ws): prep + proven cooperative hysteresis ----
__global__ __launch_bounds__(256) void canny_prep(
    const float* __restrict__ x, u64* __restrict__ weakG,
    u64* __restrict__ strongG, unsigned int* __restrict__ flags)
{
    __shared__ int imgS[20][68];
    __shared__ int magS[18][68];
    const int tid = threadIdx.x;
    const int tx0 = blockIdx.x * 64;
    const int ty0 = blockIdx.y * 16;

    if (flags && blockIdx.x == 0 && blockIdx.y == 0 && tid < 2) flags[tid] = 0u;

    for (int idx = tid; idx < 20 * 68; idx += 256) {
        int r = idx / 68, c = idx - r * 68;
        int gy = ty0 - 2 + r; gy = gy < 0 ? 0 : (gy > HH - 1 ? HH - 1 : gy);
        int gx = tx0 - 2 + c; gx = gx < 0 ? 0 : (gx > WW - 1 ? WW - 1 : gx);
        float v = floorf(x[gy * WW + gx] * 255.0f);
        v = fminf(fmaxf(v, 0.0f), 255.0f);
        imgS[r][c] = (int)v;
    }
    __syncthreads();

    for (int idx = tid; idx < 18 * 66; idx += 256) {
        int r = idx / 66, c = idx - r * 66;
        int a00 = imgS[r][c],     a01 = imgS[r][c + 1],     a02 = imgS[r][c + 2];
        int a10 = imgS[r + 1][c],                           a12 = imgS[r + 1][c + 2];
        int a20 = imgS[r + 2][c], a21 = imgS[r + 2][c + 1], a22 = imgS[r + 2][c + 2];
        int gxv = (a02 + 2 * a12 + a22) - (a00 + 2 * a10 + a20);
        int gyv = (a20 + 2 * a21 + a22) - (a00 + 2 * a01 + a02);
        magS[r][c] = abs(gxv) + abs(gyv);
    }
    __syncthreads();

    const int lane = tid & 63;
    const int wv = tid >> 6;
    for (int i = 0; i < 4; ++i) {
        int rr = wv * 4 + i;
        int gyp = ty0 + rr;
        int r = rr + 1, c = lane + 1;
        int a00 = imgS[rr + 1][lane + 1], a01 = imgS[rr + 1][lane + 2], a02 = imgS[rr + 1][lane + 3];
        int a10 = imgS[rr + 2][lane + 1],                               a12 = imgS[rr + 2][lane + 3];
        int a20 = imgS[rr + 3][lane + 1], a21 = imgS[rr + 3][lane + 2], a22 = imgS[rr + 3][lane + 3];
        int gxv = (a02 + 2 * a12 + a22) - (a00 + 2 * a10 + a20);
        int gyv = (a20 + 2 * a21 + a22) - (a00 + 2 * a01 + a02);
        int mag = magS[r][c];
        int cls = dirClass(gxv, gyv);
        int n1, n2;
        if (cls == 0)      { n1 = magS[r][c + 1];     n2 = magS[r][c - 1]; }
        else if (cls == 1) { n1 = magS[r - 1][c + 1]; n2 = magS[r + 1][c - 1]; }
        else if (cls == 2) { n1 = magS[r - 1][c];     n2 = magS[r + 1][c]; }
        else               { n1 = magS[r - 1][c - 1]; n2 = magS[r + 1][c + 1]; }

        bool keep = (mag >= n1) && (mag > n2) && (gyp > 0) && (gyp < HH - 1);
        bool weak = keep && (mag > 100);
        bool strong = keep && (mag > 200);
        u64 ww = __ballot(weak);
        u64 sw = __ballot(strong);
        if (lane == 0) {
            u64 mm = ~0ull;
            if (tx0 == 0) mm &= ~1ull;
            if (tx0 + 64 == WW) mm &= ~(1ull << 63);
            int widx = gyp * WPR + (tx0 >> 6);
            weakG[widx] = ww & mm;
            strongG[widx] = sw & mm;
        }
    }
}

__global__ __launch_bounds__(256) void canny_hyst(
    const u64* __restrict__ weakG, u64* __restrict__ edgeG,
    unsigned int* __restrict__ flags, float* __restrict__ out)
{
    cg::grid_group grid = cg::this_grid();
    const int tid = threadIdx.x;
    const int b = blockIdx.x;
    const int r = tid >> 5;
    const int c = tid & 31;
    const int row0 = b * 8;
    __shared__ u64 weakL[8][32];
    __shared__ u64 edgeL[10][32];
    __shared__ int sChg[2];
    __shared__ int sAny;

    weakL[r][c] = weakG[(row0 + r) * WPR + c];
    edgeL[r + 1][c] = edgeG[(row0 + r) * WPR + c];

    int iter = 0;
    for (;;) {
        if (tid < 32) {
            u64 v = 0;
            if (b > 0) v = __hip_atomic_load(&edgeG[(row0 - 1) * WPR + tid],
                                             __ATOMIC_RELAXED, __HIP_MEMORY_SCOPE_AGENT);
            edgeL[0][tid] = v;
        } else if (tid < 64) {
            int cc = tid - 32;
            u64 v = 0;
            if (b < (int)gridDim.x - 1)
                v = __hip_atomic_load(&edgeG[(row0 + 8) * WPR + cc],
                                      __ATOMIC_RELAXED, __HIP_MEMORY_SCOPE_AGENT);
            edgeL[9][cc] = v;
        }
        if (tid == 0) sAny = 0;
        if (tid < 2) sChg[tid] = 0;
        __syncthreads();

        int p = 0;
        for (;;) {
            u64 up = edgeL[r][c],     upl = c ? edgeL[r][c - 1] : 0,     upr = (c < 31) ? edgeL[r][c + 1] : 0;
            u64 mi = edgeL[r + 1][c], mil = c ? edgeL[r + 1][c - 1] : 0, mir = (c < 31) ? edgeL[r + 1][c + 1] : 0;
            u64 dn = edgeL[r + 2][c], dnl = c ? edgeL[r + 2][c - 1] : 0, dnr = (c < 31) ? edgeL[r + 2][c + 1] : 0;
            u64 A = up | (up << 1) | (up >> 1) | (upl >> 63) | (upr << 63);
            u64 B = mi | (mi << 1) | (mi >> 1) | (mil >> 63) | (mir << 63);
            u64 C = dn | (dn << 1) | (dn >> 1) | (dnl >> 63) | (dnr << 63);
            u64 ne = mi | (weakL[r][c] & (A | B | C));
            bool chg = (ne != mi);
            __syncthreads();
            edgeL[r + 1][c] = ne;
            if (chg) { sChg[p] = 1; sAny = 1; }
            if (tid == 0) sChg[p ^ 1] = 0;
            __syncthreads();
            if (!sChg[p]) break;
            p ^= 1;
        }

        if (sAny) edgeG[(row0 + r) * WPR + c] = edgeL[r + 1][c];
        if (sAny && tid == 0) atomicOr(&flags[iter & 1], 1u);
        __threadfence();
        grid.sync();
        unsigned fl2 = __hip_atomic_load(&flags[iter & 1], __ATOMIC_ACQUIRE, __HIP_MEMORY_SCOPE_AGENT);
        if (tid == 0) flags[(iter + 1) & 1] = 0u;
        __threadfence();
        grid.sync();
        if (fl2 == 0) break;
        ++iter;
    }

    for (int chn = 0; chn < 3; ++chn) {
        for (int rr = 0; rr < 8; ++rr) {
            size_t base2 = ((size_t)chn * HH + (size_t)(row0 + rr)) * WW;
            for (int k = tid; k < 512; k += 256) {
                u64 w = edgeL[rr + 1][k >> 4];
                int sh = (k & 15) * 4;
                float4 v;
                v.x = (float)((w >> sh) & 1ull);
                v.y = (float)((w >> (sh + 1)) & 1ull);
                v.z = (float)((w >> (sh + 2)) & 1ull);
                v.w = (float)((w >> (sh + 3)) & 1ull);
                *reinterpret_cast<float4*>(out + base2 + (size_t)k * 4) = v;
            }
        }
    }
}

extern "C" void kernel_launch(void* const* d_in, const int* in_sizes, int n_in,
                              void* d_out, int out_size, void* d_ws, size_t ws_size,
                              hipStream_t stream) {
    const float* x = (const float*)d_in[0];
    float* out = (float*)d_out;

    const size_t BM = (size_t)NWORDS * 8;          // 512 KB per bitmap
    const size_t need = 3 * BM + (size_t)NPIX * 4; // weak+edge+pend bitmaps + labels

    if (ws_size >= need) {
        u64* weakG    = (u64*)d_ws;
        u64* edgeBits = weakG + NWORDS;
        u64* pendBits = edgeBits + NWORDS;
        int* f = (int*)(pendBits + NWORDS);

        hipLaunchKernelGGL(canny_tile, dim3(32, 32), dim3(512), 0, stream,
                           x, weakG, edgeBits, pendBits, f);
        hipLaunchKernelGGL(canny_boundary, dim3((65536 + 31 * 2048 + 255) / 256), dim3(256),
                           0, stream, weakG, f);
        hipLaunchKernelGGL(canny_edgefuse, dim3(NPIX / 4096), dim3(256), 0, stream,
                           edgeBits, pendBits, f, out);
    } else {
        u64* edgeG = (u64*)d_ws;
        u64* weakG = edgeG + NWORDS;
        unsigned int* flags = (unsigned int*)(weakG + NWORDS);
        hipLaunchKernelGGL(canny_prep, dim3(WW / 64, HH / 16), dim3(256), 0, stream,
                           x, weakG, edgeG, flags);
        void* args[] = { (void*)&weakG, (void*)&edgeG, (void*)&flags, (void*)&out };
        hipLaunchCooperativeKernel((void*)canny_hyst, dim3(256), dim3(256), args, 0, stream);
    }
}